// Round 11
// baseline (63163.635 us; speedup 1.0000x reference)
//
#include <hip/hip_runtime.h>

// Persistent-grid DNC encoder for MI355X (gfx950).
// R15 = R11 VERBATIM + two-region time-dilation probe (R14 follow-up).
// R14 measured: phase C (B1 -> r-drain) = 34.3 us of the 44.1 us step;
// handoff chain only ~10 us. This round splits phase C into
//   T_xi  = B1 -> (barrier after xi write)
//   T_rest= (barrier after xi) -> r-drain
// via asymmetric dilation: block 0 spins 8*T_xi + 2*T_rest extra at exit.
// Decode (with T_xi + T_rest = 34.3 us from R14):
//   T_xi/step = ((dur_us - 11290)/256 - 2*34.3) / 6
// dur ~33-38ms -> interior is the sink; dur ~55-70ms -> xi is the sink.

constexpr int NBLK = 128;
constexpr int BS   = 256;
constexpr int BQ   = 32;
constexpr int TT   = 256;
constexpr int HH   = 512;
constexpr int RH   = 4;
constexpr int NC   = 64;
constexpr int XI   = 471;
constexpr int KG   = 1280;    // gates K = 512(x)+256(r)+512(h)
constexpr int KGP  = 1288;    // padded LDS K stride (bf16)
constexpr int WOP  = 776;     // padded W_out K stride
constexpr float CLIPV = 50000.0f;
constexpr float EPSV  = 1e-6f;

typedef __bf16 bf16x8 __attribute__((ext_vector_type(8)));
typedef float  f32x4  __attribute__((ext_vector_type(4)));
typedef unsigned long long u64;

// ---- LDS layout (bytes) ----
constexpr int OFF_WG   = 0;                      // 16*KGP bf16 = 41216
constexpr int OFF_WO   = OFF_WG  + 16*KGP*2;     // 16*WOP bf16 = 24832
constexpr int OFF_GT   = OFF_WO  + 16*WOP*2;     // 32*17 f32   = 2176
constexpr int OFF_CST  = OFF_GT  + 32*17*4;      // 128 f32     = 512
constexpr int OFF_HLB  = OFF_CST + 512;          // 512 bf16    = 1024
constexpr int OFF_DNC  = OFF_HLB + 1024;
constexpr int D_M    = 0;                        // 64*65 f32
constexpr int D_L    = D_M   + 64*65*4;
constexpr int D_XIR  = D_L   + 64*65*4;          // 480 f32
constexpr int D_WR   = D_XIR + 480*4;
constexpr int D_FWD  = D_WR  + 256*4;
constexpr int D_BWD  = D_FWD + 256*4;
constexpr int D_SIMR = D_BWD + 256*4;
constexpr int D_VEC  = D_SIMR+ 256*4;            // 8 arrays of 64 f32
constexpr int D_SCAL = D_VEC + 8*64*4;           // 32 f32
constexpr int SMEM_BYTES = OFF_DNC + D_SCAL + 32*4;   // 111232

// ---- workspace layout (bytes) ----
constexpr size_t WS_HFLG = 0;                          // hdone counter line
constexpr size_t WS_RFLG = 8192;                       // rdone counter line
constexpr size_t WS_HBUF = 8192 + 2048;                // 2*32*512 bf16 = 65536
constexpr size_t WS_RBUF = WS_HBUF + 65536;            // 32*256 bf16   = 16384
constexpr size_t WS_WXBT = WS_RBUF + 16384;            // 480*512 bf16  = 491520
constexpr size_t WS_EMB  = WS_WXBT + 491520;           // 8192*512 bf16 = 8388608
constexpr size_t WS_MIN  = WS_WXBT + 491520;
constexpr size_t WS_FULL = WS_EMB + 8388608;
constexpr size_t WS_HBUFD = WS_FULL;                   // 2*32*512 bf16 = 65536
constexpr size_t HBUFD_BYTES = 2ull * BQ * HH * 2;
constexpr size_t WS_FULL2 = WS_HBUFD + HBUFD_BYTES;
constexpr size_t WS_ZERO = WS_RBUF + 16384;            // counters + hbuf + rbuf

__device__ __forceinline__ unsigned short f2b(float f) {
  unsigned u = __builtin_bit_cast(unsigned, f);
  u += 0x7fffu + ((u >> 16) & 1u);
  return (unsigned short)(u >> 16);
}
__device__ __forceinline__ float sigf(float x) { return 1.0f / (1.0f + expf(-x)); }
__device__ __forceinline__ float softplusf(float x) { return (x > 20.0f) ? x : log1pf(expf(x)); }
__device__ __forceinline__ float wsum(float v) {
  #pragma unroll
  for (int o = 32; o; o >>= 1) v += __shfl_xor(v, o, 64);
  return v;
}
__device__ __forceinline__ float wmaxr(float v) {
  #pragma unroll
  for (int o = 32; o; o >>= 1) v = fmaxf(v, __shfl_xor(v, o, 64));
  return v;
}
__device__ __forceinline__ f32x4 mfma16(bf16x8 a, bf16x8 b, f32x4 c) {
  return __builtin_amdgcn_mfma_f32_16x16x32_bf16(a, b, c, 0, 0, 0);
}
__device__ __forceinline__ u64 realt() {
  return __builtin_amdgcn_s_memrealtime();
}

// MALL write-through / MALL-direct (relaxed agent atomics)
__device__ __forceinline__ void st_u64(u64* p, u64 v) {
  __hip_atomic_store(p, v, __ATOMIC_RELAXED, __HIP_MEMORY_SCOPE_AGENT);
}
__device__ __forceinline__ u64 ld_u64(const u64* p) {
  return __hip_atomic_load(p, __ATOMIC_RELAXED, __HIP_MEMORY_SCOPE_AGENT);
}
__device__ __forceinline__ unsigned ld_flag(const unsigned* p) {
  return __hip_atomic_load(p, __ATOMIC_RELAXED, __HIP_MEMORY_SCOPE_AGENT);
}
__device__ __forceinline__ void add_flag(unsigned* p) {
  __hip_atomic_fetch_add(p, 1u, __ATOMIC_RELAXED, __HIP_MEMORY_SCOPE_AGENT);
}
struct alignas(16) U64x2 { u64 a, b; };
__device__ __forceinline__ bf16x8 ld_bf16x8_mall(const unsigned short* p) {
  U64x2 v;
  v.a = ld_u64((const u64*)p);
  v.b = ld_u64((const u64*)p + 1);
  return __builtin_bit_cast(bf16x8, v);
}

// wave 0 polls a single shared counter (one request per round), block release
__device__ __forceinline__ void wait_cnt(const unsigned* cnt, unsigned target) {
  if ((threadIdx.x >> 6) == 0) {
    while (ld_flag(cnt) < target) { /* tight spin, single line */ }
  }
  __builtin_amdgcn_fence(__ATOMIC_ACQUIRE, "workgroup");
  __syncthreads();
}

__global__ __launch_bounds__(BS, 1) void dnc_kernel(
    const int* __restrict__ src, const float* __restrict__ emb,
    const float* __restrict__ Wih, const float* __restrict__ Whh,
    const float* __restrict__ b_lstm, const float* __restrict__ W_xi,
    const float* __restrict__ b_xi, const float* __restrict__ W_out,
    const float* __restrict__ b_out, float* __restrict__ out,
    unsigned* __restrict__ hdone, unsigned* __restrict__ rdone,
    unsigned short* __restrict__ hbuf, unsigned short* __restrict__ rbuf,
    unsigned short* __restrict__ wxbT_, unsigned short* __restrict__ embbuf_,
    unsigned short* __restrict__ hbufD)
{
  extern __shared__ char smem[];
  __bf16* lWg  = (__bf16*)(smem + OFF_WG);
  __bf16* lWo  = (__bf16*)(smem + OFF_WO);
  float*  gt   = (float*)(smem + OFF_GT);
  float*  cst  = (float*)(smem + OFF_CST);
  __bf16* hlb  = (__bf16*)(smem + OFF_HLB);
  char*   dnc  = smem + OFF_DNC;
  float* Ml   = (float*)(dnc + D_M);
  float* Ll   = (float*)(dnc + D_L);
  float* xir  = (float*)(dnc + D_XIR);
  float* wrl  = (float*)(dnc + D_WR);
  float* fwd  = (float*)(dnc + D_FWD);
  float* bwd  = (float*)(dnc + D_BWD);
  float* simr = (float*)(dnc + D_SIMR);
  float* uu   = (float*)(dnc + D_VEC);
  float* pp   = uu + 64;
  float* wwl  = uu + 128;
  float* aas  = uu + 192;
  float* nrmo = uu + 256;
  float* nrmn = uu + 320;
  float* simw = uu + 384;
  float* er   = uu + 448;
  float* scal = (float*)(dnc + D_SCAL);
  // scal: [0]beta_w [1]g_a [2]g_w [3]wknrm [4..7]beta_r [8..11]rkn [12..15]free [16..27]pi

  const int tid  = threadIdx.x;
  const int blk  = blockIdx.x;
  const int lane = tid & 63;
  const int wv   = tid >> 6;
  const int q    = lane >> 4;
  const int n16  = lane & 15;
  const int j0   = blk << 2;    // h slice: columns j0..j0+3
  const __bf16* wxbT = (const __bf16*)wxbT_;
  const __bf16* embbuf = (const __bf16*)embbuf_;
  const bool is_dnc = (blk < BQ);
  const bool is_y   = (blk >= 64 && blk < 96);

  // two-region probe accumulators (block 0 only pays)
  u64 tc0 = 0, Txi = 0, Trest = 0;

  // ---------------- prepass ----------------
  for (int e = tid; e < 16 * KG; e += BS) {
    int k = e >> 4, cc = e & 15;
    int gcol = ((cc >> 2) << 9) + j0 + (cc & 3);   // gate*512 + h-col
    float w = (k < 768) ? Wih[k * 2048 + gcol] : Whh[(k - 768) * 2048 + gcol];
    lWg[cc * KGP + k] = (__bf16)w;
  }
  if (is_y) {
    for (int e = tid; e < 16 * 768; e += BS) {
      int k = e >> 4, cc = e & 15;
      int col = ((blk - 64) << 4) + cc;
      lWo[cc * WOP + k] = (__bf16)W_out[k * HH + col];
    }
  }
  if (wxbT_) {   // W_xi^T -> bf16 [col][k] (MALL write-through)
    for (int f = blk * BS + tid; f < XI * 128; f += NBLK * BS) {
      int col = f >> 7, k4 = (f & 127) << 2;
      u64 pk = 0;
      #pragma unroll
      for (int j = 0; j < 4; ++j) {
        unsigned short us = f2b(W_xi[(size_t)(k4 + j) * XI + col]);
        pk |= (u64)us << (16 * j);
      }
      st_u64((u64*)(wxbT_ + (size_t)col * 512 + k4), pk);
    }
  }
  if (embbuf_) { // gather emb[src] -> bf16 (MALL write-through)
    for (int rr = blk * 2 + (tid >> 7); rr < BQ * TT; rr += NBLK * 2) {
      const int t128 = tid & 127;
      const float* s = emb + (size_t)src[rr] * HH;
      float4 v = *(const float4*)(s + t128 * 4);
      u64 pk = (u64)f2b(v.x) | ((u64)f2b(v.y) << 16)
             | ((u64)f2b(v.z) << 32) | ((u64)f2b(v.w) << 48);
      st_u64((u64*)(embbuf_ + (size_t)rr * HH + t128 * 4), pk);
    }
  }
  if (tid < 128) cst[tid] = 0.0f;
  if (is_dnc) {
    for (int e = tid; e < 64 * 65; e += BS) { Ml[e] = 0.0f; Ll[e] = 0.0f; }
    if (tid < 64) { uu[tid] = 0.0f; pp[tid] = 0.0f; wwl[tid] = 0.0f; }
    wrl[tid] = 0.0f;
  }
  __syncthreads();
  if (tid == 0) add_flag(hdone);        // prepass published (+1 of 128)

  // persistent gates accumulators (waves 0,1)
  f32x4 ax0 = {0.f, 0.f, 0.f, 0.f}, ax1 = {0.f, 0.f, 0.f, 0.f};
  const int bb = ((wv & 1) << 4) + n16;          // gates A-row (waves 0,1)

  // x-part: 16 MFMAs (embedding of step tt)
  auto x_mfmas = [&](int tt) {
    const __bf16* eb = embbuf ? (embbuf + ((size_t)bb * TT + tt) * HH) : nullptr;
    const float* ep = embbuf ? nullptr
                             : (emb + (size_t)src[bb * TT + tt] * HH + (q << 3));
    #pragma unroll
    for (int ks = 0; ks < 16; ++ks) {
      const int kq = (ks << 5) + (q << 3);
      bf16x8 A;
      if (eb) {
        A = *(const bf16x8*)(eb + kq);
      } else {
        const float* p = ep + (ks << 5);
        #pragma unroll
        for (int j = 0; j < 8; ++j) A[j] = (__bf16)p[j];
      }
      bf16x8 Bf = *(const bf16x8*)(lWg + n16 * KGP + kq);
      if (ks & 1) ax1 = mfma16(A, Bf, ax1); else ax0 = mfma16(A, Bf, ax0);
    }
  };
  // h-part: 16 MFMAs reading h(slot) MALL-direct
  auto h_mfmas = [&](int slot) {
    const unsigned short* hp = hbuf + slot * (BQ * HH);
    #pragma unroll
    for (int ks = 16; ks < 32; ++ks) {
      const int off = ((ks - 16) << 5) + (q << 3);
      bf16x8 A = ld_bf16x8_mall(hp + bb * HH + off);
      bf16x8 Bf = *(const bf16x8*)(lWg + n16 * KGP + 768 + off);
      if (ks & 1) ax1 = mfma16(A, Bf, ax1); else ax0 = mfma16(A, Bf, ax0);
    }
  };
  // r-part: 8 MFMAs reading rbuf MALL-direct; then write gt
  auto r_mfmas = [&]() {
    #pragma unroll
    for (int ks = 32; ks < 40; ++ks) {
      const int off = ((ks - 32) << 5) + (q << 3);
      bf16x8 A = ld_bf16x8_mall(rbuf + bb * (RH * NC) + off);
      bf16x8 Bf = *(const bf16x8*)(lWg + n16 * KGP + 512 + off);
      if (ks & 1) ax1 = mfma16(A, Bf, ax1); else ax0 = mfma16(A, Bf, ax0);
    }
    const int gcol = ((n16 >> 2) << 9) + j0 + (n16 & 3);
    const float bias = b_lstm[gcol];
    #pragma unroll
    for (int j = 0; j < 4; ++j)
      gt[(((wv & 1) << 4) + (q << 2) + j) * 17 + n16] = ax0[j] + ax1[j] + bias;
  };
  // y(t-1): waves 2,3 of y-blocks; needs h(t-1) and r(t-1)
  auto do_y = [&](int t) {
    const unsigned short* hp = hbuf + ((t + 1) & 1) * (BQ * HH);
    const int mt = wv - 2;
    const int bby = (mt << 4) + n16;
    f32x4 a0 = {0.f, 0.f, 0.f, 0.f}, a1 = {0.f, 0.f, 0.f, 0.f};
    #pragma unroll
    for (int ks = 0; ks < 24; ++ks) {
      const int kq = (ks << 5) + (q << 3);
      bf16x8 A = (ks < 16) ? ld_bf16x8_mall(hp + bby * HH + kq)
                           : ld_bf16x8_mall(rbuf + bby * (RH * NC) + (kq - 512));
      bf16x8 Bf = *(const bf16x8*)(lWo + n16 * WOP + kq);
      if (ks & 1) a1 = mfma16(A, Bf, a1); else a0 = mfma16(A, Bf, a0);
    }
    const int col = ((blk - 64) << 4) + n16;
    const float bias = b_out[col];
    #pragma unroll
    for (int j = 0; j < 4; ++j) {
      int row = (mt << 4) + (q << 2) + j;
      float y = a0[j] + a1[j] + bias;
      y = fminf(fmaxf(y, -CLIPV), CLIPV);
      out[(size_t)row * (TT * HH) + (size_t)(t - 1) * HH + col] = y;
    }
  };

  // pre-loop: wait all prepass, then x-part(0). h(-1)=0, r(-1)=0.
  wait_cnt(hdone, 128u);
  if (wv < 2) x_mfmas(0);

  for (int t = 0; t < TT; ++t) {
    unsigned short* hcur = hbuf + (t & 1) * (BQ * HH);

    if (t > 0) wait_cnt(rdone, 32u * (unsigned)t);  // r(t-1) (t=0: zeros)
    if (wv < 2) {
      r_mfmas();                          // gates(t) complete -> gt
    } else if (is_y && t > 0) {
      do_y(t);                            // y(t-1): h(t-1), r(t-1)
    }
    __syncthreads();
    if (tid < BQ) {                       // LSTM: batch=tid, 4 h-cols
      const int b = tid;
      u64 hv = 0;
      #pragma unroll
      for (int i = 0; i < 4; ++i) {
        float g_i = gt[b * 17 + i],     g_f = gt[b * 17 + 4 + i];
        float g_g = gt[b * 17 + 8 + i], g_o = gt[b * 17 + 12 + i];
        float c = cst[b * 4 + i];
        c = sigf(g_f) * c + sigf(g_i) * tanhf(g_g);
        float h = sigf(g_o) * tanhf(c);
        cst[b * 4 + i] = c;
        hv |= (u64)f2b(h) << (16 * i);
      }
      if (hbufD)                          // DNC mailbox: lands earliest
        st_u64((u64*)(hbufD + (size_t)(t & 1) * (BQ * HH) + (size_t)b * HH + j0), hv);
      st_u64((u64*)(hcur + b * HH + j0), hv);
    }
    __syncthreads();                      // drain h stores to MALL
    if (tid == 0) add_flag(hdone);        // h(t) published

    if (is_dnc) {
      // ---------------- phase C(t) ----------------
      if (hbufD) {
        if (wv >= 2) {                    // waves 2,3: destructive mailbox read
          const int g = tid - 128;        // 0..127 -> h cols 4g..4g+3
          u64* mb = (u64*)(hbufD + (size_t)(t & 1) * (BQ * HH) + (size_t)blk * HH) + g;
          u64 hv = ld_u64(mb);
          while (hv == ~0ull) { hv = ld_u64(mb); }
          st_u64(mb, ~0ull);              // re-arm sentinel (drained at B1)
          #pragma unroll
          for (int i = 0; i < 4; ++i)
            hlb[g * 4 + i] = __builtin_bit_cast(__bf16, (unsigned short)(hv >> (16 * i)));
        }
      } else {
        wait_cnt(hdone, 128u * (unsigned)(t + 2));  // fallback: full h(t)
        if (tid < 128) {
          u64 hv = ld_u64((const u64*)(hcur + blk * HH + tid * 4));
          #pragma unroll
          for (int i = 0; i < 4; ++i)
            hlb[tid * 4 + i] = __builtin_bit_cast(__bf16, (unsigned short)(hv >> (16 * i)));
        }
      }
      __syncthreads();                    // B1: h in LDS
      if (blk == 0) tc0 = realt();        // ---- probe: xi region start ----
      // xi = h @ W_xi + b_xi via MFMA
      {
        constexpr int TPW = 8;
        f32x4 acc[TPW];
        #pragma unroll
        for (int i = 0; i < TPW; ++i) acc[i] = f32x4{0.f, 0.f, 0.f, 0.f};
        const int ct0 = wv * TPW;
        const int ntile = (ct0 + TPW <= 30) ? TPW : (30 - ct0);
        for (int kt = 0; kt < 16; ++kt) {
          bf16x8 Bf = {};
          if (n16 == 0) Bf = *(const bf16x8*)(hlb + kt * 32 + (q << 3));
          if (wxbT) {
            #pragma unroll
            for (int i = 0; i < TPW; ++i) {
              if (i < ntile) {
                const __bf16* ap = wxbT + (size_t)((ct0 + i) * 16 + n16) * 512
                                        + kt * 32 + (q << 3);
                acc[i] = mfma16(*(const bf16x8*)ap, Bf, acc[i]);
              }
            }
          } else {
            #pragma unroll
            for (int i = 0; i < TPW; ++i) {
              if (i < ntile) {
                const int col = (ct0 + i) * 16 + n16;
                bf16x8 Af;
                #pragma unroll
                for (int j = 0; j < 8; ++j)
                  Af[j] = (col < XI) ? (__bf16)W_xi[(size_t)(kt * 32 + (q << 3) + j) * XI + col]
                                     : (__bf16)0.0f;
                acc[i] = mfma16(Af, Bf, acc[i]);
              }
            }
          }
        }
        if (n16 == 0) {
          const int rowb = (lane >> 4) * 4;
          #pragma unroll
          for (int i = 0; i < TPW; ++i) {
            if (i < ntile) {
              #pragma unroll
              for (int j = 0; j < 4; ++j) {
                int col = (ct0 + i) * 16 + rowb + j;
                if (col < XI) xir[col] = acc[i][j] + b_xi[col];
              }
            }
          }
        }
      }
      __syncthreads();
      if (blk == 0) {                     // ---- probe: xi end / rest start ----
        u64 tm = realt();
        Txi += tm - tc0;
        tc0 = tm;
      }
      if (tid == 0) {
        scal[0] = 1.0f + softplusf(xir[324]);   // beta_w
        scal[1] = sigf(xir[457]);               // g_a
        scal[2] = sigf(xir[458]);               // g_w
      }
      if (tid >= 4 && tid < 8) {
        int r = tid - 4;
        scal[4 + r]  = 1.0f + softplusf(xir[256 + r]);  // beta_r
        scal[12 + r] = sigf(xir[453 + r]);              // free
        float p0 = xir[459 + r * 3], p1 = xir[460 + r * 3], p2 = xir[461 + r * 3];
        float m = fmaxf(p0, fmaxf(p1, p2));
        float e0 = expf(p0 - m), e1 = expf(p1 - m), e2 = expf(p2 - m);
        float s = e0 + e1 + e2;
        scal[16 + r * 3 + 0] = e0 / s;
        scal[16 + r * 3 + 1] = e1 / s;
        scal[16 + r * 3 + 2] = e2 / s;
      }
      if (tid >= 64 && tid < 128) er[tid - 64] = sigf(xir[325 + (tid - 64)]);
      __syncthreads();
      // -- old norms / write-key sim / usage + stable sort + allocation
      if (wv == 0) {
        float s = 0.f;
        for (int w = 0; w < 64; ++w) { float m = Ml[lane * 65 + w]; s += m * m; }
        nrmo[lane] = sqrtf(s) + EPSV;
      } else if (wv == 1) {
        float d = 0.f;
        for (int w = 0; w < 64; ++w) d += Ml[lane * 65 + w] * xir[260 + w];
        simw[lane] = d;
        float v = xir[260 + lane];
        float s2 = wsum(v * v);
        if (lane == 0) scal[3] = sqrtf(s2) + EPSV;
      } else if (wv == 2) {
        float psi = 1.f;
        #pragma unroll
        for (int r = 0; r < 4; ++r) psi *= (1.f - scal[12 + r] * wrl[r * 64 + lane]);
        float un = uu[lane], w_ = wwl[lane];
        un = (un + w_ - un * w_) * psi;
        uu[lane] = un;
        // stable bitonic argsort ascending by (u, index)
        float v = un; int id = lane;
        for (int k = 2; k <= 64; k <<= 1) {
          for (int j2 = k >> 1; j2 > 0; j2 >>= 1) {
            float ov = __shfl_xor(v, j2, 64);
            int   oi = __shfl_xor(id, j2, 64);
            bool up    = ((lane & k) == 0);
            bool lower = ((lane & j2) == 0);
            bool lt = (v < ov) || (v == ov && id < oi);
            bool keep = (lower == up) ? lt : !lt;
            if (!keep) { v = ov; id = oi; }
          }
        }
        float cp = v;
        for (int d2 = 1; d2 < 64; d2 <<= 1) {
          float o = __shfl_up(cp, d2, 64);
          if (lane >= d2) cp *= o;
        }
        float pe = __shfl_up(cp, 1, 64);
        if (lane == 0) pe = 1.0f;
        aas[id] = (1.0f - v) * pe;
      }
      __syncthreads();
      // -- write content weights -> ww
      if (wv == 0) {
        float x = simw[lane] / (nrmo[lane] * scal[3]) * scal[0];
        float mx = wmaxr(x);
        float e = expf(x - mx);
        float s = wsum(e);
        float cw = e / s;
        wwl[lane] = scal[2] * (scal[1] * aas[lane] + (1.f - scal[1]) * cw);
      }
      __syncthreads();
      // -- M and L updates (old p)
      {
        const int n = tid >> 2, c4 = (tid & 3) << 4;
        float wwn = wwl[n];
        #pragma unroll
        for (int w = 0; w < 16; ++w) {
          int wj = c4 + w;
          Ml[n * 65 + wj] = Ml[n * 65 + wj] * (1.f - wwn * er[wj]) + wwn * xir[389 + wj];
        }
        #pragma unroll
        for (int w = 0; w < 16; ++w) {
          int m2 = c4 + w;
          float Lv = (n == m2) ? 0.f
                   : ((1.f - wwn - wwl[m2]) * Ll[n * 65 + m2] + wwn * pp[m2]);
          Ll[n * 65 + m2] = Lv;
        }
      }
      __syncthreads();
      // -- fwd/bwd (old wr, new L), read-key sims (new M), new norms
      {
        float f = 0.f, bw2 = 0.f, d = 0.f;
        for (int m2 = 0; m2 < 64; ++m2) {
          float wrm = wrl[wv * 64 + m2];
          f   += Ll[lane * 65 + m2] * wrm;
          bw2 += Ll[m2 * 65 + lane] * wrm;
        }
        fwd[wv * 64 + lane] = f;
        bwd[wv * 64 + lane] = bw2;
        for (int w = 0; w < 64; ++w) d += Ml[lane * 65 + w] * xir[wv * 64 + w];
        simr[wv * 64 + lane] = d;
        float v = xir[wv * 64 + lane];
        float s2 = wsum(v * v);
        if (lane == 0) scal[8 + wv] = sqrtf(s2) + EPSV;
        if (wv == 0) {
          float s = 0.f;
          for (int w = 0; w < 64; ++w) { float m = Ml[lane * 65 + w]; s += m * m; }
          nrmn[lane] = sqrtf(s) + EPSV;
        }
      }
      __syncthreads();
      // -- read content weights, new wr, p update
      {
        float x = simr[wv * 64 + lane] / (nrmn[lane] * scal[8 + wv]) * scal[4 + wv];
        float mx = wmaxr(x);
        float e = expf(x - mx);
        float s = wsum(e);
        float cw = e / s;
        float wrn = scal[16 + wv * 3 + 0] * bwd[wv * 64 + lane]
                  + scal[16 + wv * 3 + 1] * cw
                  + scal[16 + wv * 3 + 2] * fwd[wv * 64 + lane];
        wrl[wv * 64 + lane] = wrn;
        if (wv == 3) {
          float s3 = wsum(wwl[lane]);
          pp[lane] = (1.f - s3) * pp[lane] + wwl[lane];
        }
      }
      __syncthreads();
      // -- r(t) = wr @ M -> rbuf (bf16 packed, MALL write-through)
      {
        float rv = 0.f;
        for (int n2 = 0; n2 < 64; ++n2) rv += wrl[wv * 64 + n2] * Ml[n2 * 65 + lane];
        unsigned v0 = f2b(rv);
        unsigned v1 = __shfl_down(v0, 1, 64);
        unsigned v2 = __shfl_down(v0, 2, 64);
        unsigned v3 = __shfl_down(v0, 3, 64);
        if ((lane & 3) == 0) {
          u64 pk = (u64)v0 | ((u64)v1 << 16) | ((u64)v2 << 32) | ((u64)v3 << 48);
          st_u64((u64*)(rbuf + blk * (RH * NC) + wv * 64 + lane), pk);
        }
      }
      __syncthreads();                    // drain r stores
      if (blk == 0) Trest += realt() - tc0;  // ---- probe: rest end ----
      if (tid == 0) add_flag(rdone);      // r(t) published
      // gates x/h parts for t+1 (after r publication -- off critical path)
      if (t < TT - 1) {
        if (hbufD) wait_cnt(hdone, 128u * (unsigned)(t + 2));  // hbuf ready
        if (wv < 2) {
          ax0 = f32x4{0.f, 0.f, 0.f, 0.f};
          ax1 = f32x4{0.f, 0.f, 0.f, 0.f};
          x_mfmas(t + 1);
          h_mfmas(t & 1);
        }
      }
    } else {
      // overlap DNC phase C with x-part(t+1); then wait h and do h-part
      if (wv < 2 && t < TT - 1) {
        ax0 = f32x4{0.f, 0.f, 0.f, 0.f};
        ax1 = f32x4{0.f, 0.f, 0.f, 0.f};
        x_mfmas(t + 1);
      }
      wait_cnt(hdone, 128u * (unsigned)(t + 2));
      if (wv < 2 && t < TT - 1) h_mfmas(t & 1);
    }
  }

  // final y(TT-1): needs r(TT-1)
  if (is_y) {
    wait_cnt(rdone, 32u * (unsigned)TT);
    if (wv >= 2) do_y(TT);
  }

  // ---- time-dilation readout: extend kernel by 8*T_xi + 2*T_rest ----
  if (blk == 0) {
    u64 tend = realt();
    u64 target = tend + 8ull * Txi + 2ull * Trest;
    while (realt() < target) { }
  }
}

extern "C" void kernel_launch(void* const* d_in, const int* in_sizes, int n_in,
                              void* d_out, int out_size, void* d_ws, size_t ws_size,
                              hipStream_t stream) {
  const int*   src    = (const int*)d_in[0];
  const float* emb    = (const float*)d_in[2];
  const float* Wih    = (const float*)d_in[3];
  const float* Whh    = (const float*)d_in[4];
  const float* b_lstm = (const float*)d_in[5];
  const float* W_xi   = (const float*)d_in[6];
  const float* b_xi   = (const float*)d_in[7];
  const float* W_out  = (const float*)d_in[8];
  const float* b_out  = (const float*)d_in[9];
  float* out = (float*)d_out;

  char* ws = (char*)d_ws;
  unsigned*       hdone  = (unsigned*)(ws + WS_HFLG);
  unsigned*       rdone  = (unsigned*)(ws + WS_RFLG);
  unsigned short* hbuf   = (unsigned short*)(ws + WS_HBUF);
  unsigned short* rbuf   = (unsigned short*)(ws + WS_RBUF);
  unsigned short* wxbT   = (ws_size >= WS_MIN)   ? (unsigned short*)(ws + WS_WXBT)  : nullptr;
  unsigned short* embbuf = (ws_size >= WS_FULL)  ? (unsigned short*)(ws + WS_EMB)   : nullptr;
  unsigned short* hbufD  = (ws_size >= WS_FULL2) ? (unsigned short*)(ws + WS_HBUFD) : nullptr;

  hipMemsetAsync(d_ws, 0, WS_ZERO, stream);   // counters + h0 + r0
  if (hbufD)
    hipMemsetAsync(ws + WS_HBUFD, 0xFF, HBUFD_BYTES, stream);  // mailbox sentinels
  hipFuncSetAttribute((const void*)dnc_kernel,
                      hipFuncAttributeMaxDynamicSharedMemorySize, SMEM_BYTES);
  dnc_kernel<<<dim3(NBLK), dim3(BS), SMEM_BYTES, stream>>>(
      src, emb, Wih, Whh, b_lstm, W_xi, b_xi, W_out, b_out, out,
      hdone, rdone, hbuf, rbuf, wxbT, embbuf, hbufD);
}

// Round 12
// 10768.397 us; speedup vs baseline: 5.8656x; 5.8656x over previous
//
#include <hip/hip_runtime.h>

// Persistent-grid DNC encoder for MI355X (gfx950).
// R16 = R11 (11.29 ms) + ONE targeted fix from the R14/R15 dilation probes:
// PROBE RESULT: phase C = 34.3 us/step, of which xi matvec = 22.7 us (51%
// of the whole 44 us step); handoff chain only ~10 us (why 10 rounds of
// sync-topology changes were null).
// CAUSE: xi's wxbT loads have 1KB lane stride -> each bf16x8 load spans 16
// cache lines; latency-serialized -> ~420cy per load+MFMA.
// FIX: store wxbT in MFMA-fragment order (per (tile,kt): 64 lanes x 16B
// contiguous = one coalesced 1KB request per load). We build wxbT in the
// prepass, so the permutation is free. Values and FP order identical ->
// bit-identical output. Probes removed.

constexpr int NBLK = 128;
constexpr int BS   = 256;
constexpr int BQ   = 32;
constexpr int TT   = 256;
constexpr int HH   = 512;
constexpr int RH   = 4;
constexpr int NC   = 64;
constexpr int XI   = 471;
constexpr int KG   = 1280;    // gates K = 512(x)+256(r)+512(h)
constexpr int KGP  = 1288;    // padded LDS K stride (bf16)
constexpr int WOP  = 776;     // padded W_out K stride
constexpr float CLIPV = 50000.0f;
constexpr float EPSV  = 1e-6f;

typedef __bf16 bf16x8 __attribute__((ext_vector_type(8)));
typedef float  f32x4  __attribute__((ext_vector_type(4)));
typedef unsigned long long u64;

// ---- LDS layout (bytes) ----
constexpr int OFF_WG   = 0;                      // 16*KGP bf16 = 41216
constexpr int OFF_WO   = OFF_WG  + 16*KGP*2;     // 16*WOP bf16 = 24832
constexpr int OFF_GT   = OFF_WO  + 16*WOP*2;     // 32*17 f32   = 2176
constexpr int OFF_CST  = OFF_GT  + 32*17*4;      // 128 f32     = 512
constexpr int OFF_HLB  = OFF_CST + 512;          // 512 bf16    = 1024
constexpr int OFF_DNC  = OFF_HLB + 1024;
constexpr int D_M    = 0;                        // 64*65 f32
constexpr int D_L    = D_M   + 64*65*4;
constexpr int D_XIR  = D_L   + 64*65*4;          // 480 f32
constexpr int D_WR   = D_XIR + 480*4;
constexpr int D_FWD  = D_WR  + 256*4;
constexpr int D_BWD  = D_FWD + 256*4;
constexpr int D_SIMR = D_BWD + 256*4;
constexpr int D_VEC  = D_SIMR+ 256*4;            // 8 arrays of 64 f32
constexpr int D_SCAL = D_VEC + 8*64*4;           // 32 f32
constexpr int SMEM_BYTES = OFF_DNC + D_SCAL + 32*4;   // 111232

// ---- workspace layout (bytes) ----
constexpr size_t WS_HFLG = 0;                          // hdone counter line
constexpr size_t WS_RFLG = 8192;                       // rdone counter line
constexpr size_t WS_HBUF = 8192 + 2048;                // 2*32*512 bf16 = 65536
constexpr size_t WS_RBUF = WS_HBUF + 65536;            // 32*256 bf16   = 16384
constexpr size_t WS_WXBT = WS_RBUF + 16384;            // 480*512 bf16  = 491520
constexpr size_t WS_EMB  = WS_WXBT + 491520;           // 8192*512 bf16 = 8388608
constexpr size_t WS_MIN  = WS_WXBT + 491520;
constexpr size_t WS_FULL = WS_EMB + 8388608;
constexpr size_t WS_HBUFD = WS_FULL;                   // 2*32*512 bf16 = 65536
constexpr size_t HBUFD_BYTES = 2ull * BQ * HH * 2;
constexpr size_t WS_FULL2 = WS_HBUFD + HBUFD_BYTES;
constexpr size_t WS_ZERO = WS_RBUF + 16384;            // counters + hbuf + rbuf

__device__ __forceinline__ unsigned short f2b(float f) {
  unsigned u = __builtin_bit_cast(unsigned, f);
  u += 0x7fffu + ((u >> 16) & 1u);
  return (unsigned short)(u >> 16);
}
__device__ __forceinline__ float sigf(float x) { return 1.0f / (1.0f + expf(-x)); }
__device__ __forceinline__ float softplusf(float x) { return (x > 20.0f) ? x : log1pf(expf(x)); }
__device__ __forceinline__ float wsum(float v) {
  #pragma unroll
  for (int o = 32; o; o >>= 1) v += __shfl_xor(v, o, 64);
  return v;
}
__device__ __forceinline__ float wmaxr(float v) {
  #pragma unroll
  for (int o = 32; o; o >>= 1) v = fmaxf(v, __shfl_xor(v, o, 64));
  return v;
}
__device__ __forceinline__ f32x4 mfma16(bf16x8 a, bf16x8 b, f32x4 c) {
  return __builtin_amdgcn_mfma_f32_16x16x32_bf16(a, b, c, 0, 0, 0);
}

// MALL write-through / MALL-direct (relaxed agent atomics)
__device__ __forceinline__ void st_u64(u64* p, u64 v) {
  __hip_atomic_store(p, v, __ATOMIC_RELAXED, __HIP_MEMORY_SCOPE_AGENT);
}
__device__ __forceinline__ u64 ld_u64(const u64* p) {
  return __hip_atomic_load(p, __ATOMIC_RELAXED, __HIP_MEMORY_SCOPE_AGENT);
}
__device__ __forceinline__ unsigned ld_flag(const unsigned* p) {
  return __hip_atomic_load(p, __ATOMIC_RELAXED, __HIP_MEMORY_SCOPE_AGENT);
}
__device__ __forceinline__ void add_flag(unsigned* p) {
  __hip_atomic_fetch_add(p, 1u, __ATOMIC_RELAXED, __HIP_MEMORY_SCOPE_AGENT);
}
struct alignas(16) U64x2 { u64 a, b; };
__device__ __forceinline__ bf16x8 ld_bf16x8_mall(const unsigned short* p) {
  U64x2 v;
  v.a = ld_u64((const u64*)p);
  v.b = ld_u64((const u64*)p + 1);
  return __builtin_bit_cast(bf16x8, v);
}

// wave 0 polls a single shared counter (one request per round), block release
__device__ __forceinline__ void wait_cnt(const unsigned* cnt, unsigned target) {
  if ((threadIdx.x >> 6) == 0) {
    while (ld_flag(cnt) < target) { /* tight spin, single line */ }
  }
  __builtin_amdgcn_fence(__ATOMIC_ACQUIRE, "workgroup");
  __syncthreads();
}

__global__ __launch_bounds__(BS, 1) void dnc_kernel(
    const int* __restrict__ src, const float* __restrict__ emb,
    const float* __restrict__ Wih, const float* __restrict__ Whh,
    const float* __restrict__ b_lstm, const float* __restrict__ W_xi,
    const float* __restrict__ b_xi, const float* __restrict__ W_out,
    const float* __restrict__ b_out, float* __restrict__ out,
    unsigned* __restrict__ hdone, unsigned* __restrict__ rdone,
    unsigned short* __restrict__ hbuf, unsigned short* __restrict__ rbuf,
    unsigned short* __restrict__ wxbT_, unsigned short* __restrict__ embbuf_,
    unsigned short* __restrict__ hbufD)
{
  extern __shared__ char smem[];
  __bf16* lWg  = (__bf16*)(smem + OFF_WG);
  __bf16* lWo  = (__bf16*)(smem + OFF_WO);
  float*  gt   = (float*)(smem + OFF_GT);
  float*  cst  = (float*)(smem + OFF_CST);
  __bf16* hlb  = (__bf16*)(smem + OFF_HLB);
  char*   dnc  = smem + OFF_DNC;
  float* Ml   = (float*)(dnc + D_M);
  float* Ll   = (float*)(dnc + D_L);
  float* xir  = (float*)(dnc + D_XIR);
  float* wrl  = (float*)(dnc + D_WR);
  float* fwd  = (float*)(dnc + D_FWD);
  float* bwd  = (float*)(dnc + D_BWD);
  float* simr = (float*)(dnc + D_SIMR);
  float* uu   = (float*)(dnc + D_VEC);
  float* pp   = uu + 64;
  float* wwl  = uu + 128;
  float* aas  = uu + 192;
  float* nrmo = uu + 256;
  float* nrmn = uu + 320;
  float* simw = uu + 384;
  float* er   = uu + 448;
  float* scal = (float*)(dnc + D_SCAL);
  // scal: [0]beta_w [1]g_a [2]g_w [3]wknrm [4..7]beta_r [8..11]rkn [12..15]free [16..27]pi

  const int tid  = threadIdx.x;
  const int blk  = blockIdx.x;
  const int lane = tid & 63;
  const int wv   = tid >> 6;
  const int q    = lane >> 4;
  const int n16  = lane & 15;
  const int j0   = blk << 2;    // h slice: columns j0..j0+3
  const __bf16* wxbT = (const __bf16*)wxbT_;
  const __bf16* embbuf = (const __bf16*)embbuf_;
  const bool is_dnc = (blk < BQ);
  const bool is_y   = (blk >= 64 && blk < 96);

  // ---------------- prepass ----------------
  for (int e = tid; e < 16 * KG; e += BS) {
    int k = e >> 4, cc = e & 15;
    int gcol = ((cc >> 2) << 9) + j0 + (cc & 3);   // gate*512 + h-col
    float w = (k < 768) ? Wih[k * 2048 + gcol] : Whh[(k - 768) * 2048 + gcol];
    lWg[cc * KGP + k] = (__bf16)w;
  }
  if (is_y) {
    for (int e = tid; e < 16 * 768; e += BS) {
      int k = e >> 4, cc = e & 15;
      int col = ((blk - 64) << 4) + cc;
      lWo[cc * WOP + k] = (__bf16)W_out[k * HH + col];
    }
  }
  if (wxbT_) {
    // W_xi -> bf16 in MFMA-FRAGMENT order (coalesced xi loads):
    // element e = ((tile*16 + kt)*64 + lane)*8 + j
    //   col = tile*16 + (lane&15)          (0 pad for col >= XI)
    //   k   = kt*32 + (lane>>4)*8 + j
    // one u64 covers j = jb..jb+3 (jb in {0,4})
    for (int w = blk * BS + tid; w < 61440; w += NBLK * BS) {
      int e = w << 2;
      int jb    = e & 7;
      int lane_ = (e >> 3) & 63;
      int f     = e >> 9;              // tile*16 + kt
      int col   = (f >> 4) * 16 + (lane_ & 15);
      int k0    = (f & 15) * 32 + (lane_ >> 4) * 8 + jb;
      u64 pk = 0;
      if (col < XI) {
        #pragma unroll
        for (int j = 0; j < 4; ++j) {
          unsigned short us = f2b(W_xi[(size_t)(k0 + j) * XI + col]);
          pk |= (u64)us << (16 * j);
        }
      }
      st_u64((u64*)wxbT_ + w, pk);
    }
  }
  if (embbuf_) { // gather emb[src] -> bf16 (MALL write-through)
    for (int rr = blk * 2 + (tid >> 7); rr < BQ * TT; rr += NBLK * 2) {
      const int t128 = tid & 127;
      const float* s = emb + (size_t)src[rr] * HH;
      float4 v = *(const float4*)(s + t128 * 4);
      u64 pk = (u64)f2b(v.x) | ((u64)f2b(v.y) << 16)
             | ((u64)f2b(v.z) << 32) | ((u64)f2b(v.w) << 48);
      st_u64((u64*)(embbuf_ + (size_t)rr * HH + t128 * 4), pk);
    }
  }
  if (tid < 128) cst[tid] = 0.0f;
  if (is_dnc) {
    for (int e = tid; e < 64 * 65; e += BS) { Ml[e] = 0.0f; Ll[e] = 0.0f; }
    if (tid < 64) { uu[tid] = 0.0f; pp[tid] = 0.0f; wwl[tid] = 0.0f; }
    wrl[tid] = 0.0f;
  }
  __syncthreads();
  if (tid == 0) add_flag(hdone);        // prepass published (+1 of 128)

  // persistent gates accumulators (waves 0,1)
  f32x4 ax0 = {0.f, 0.f, 0.f, 0.f}, ax1 = {0.f, 0.f, 0.f, 0.f};
  const int bb = ((wv & 1) << 4) + n16;          // gates A-row (waves 0,1)

  // x-part: 16 MFMAs (embedding of step tt)
  auto x_mfmas = [&](int tt) {
    const __bf16* eb = embbuf ? (embbuf + ((size_t)bb * TT + tt) * HH) : nullptr;
    const float* ep = embbuf ? nullptr
                             : (emb + (size_t)src[bb * TT + tt] * HH + (q << 3));
    #pragma unroll
    for (int ks = 0; ks < 16; ++ks) {
      const int kq = (ks << 5) + (q << 3);
      bf16x8 A;
      if (eb) {
        A = *(const bf16x8*)(eb + kq);
      } else {
        const float* p = ep + (ks << 5);
        #pragma unroll
        for (int j = 0; j < 8; ++j) A[j] = (__bf16)p[j];
      }
      bf16x8 Bf = *(const bf16x8*)(lWg + n16 * KGP + kq);
      if (ks & 1) ax1 = mfma16(A, Bf, ax1); else ax0 = mfma16(A, Bf, ax0);
    }
  };
  // h-part: 16 MFMAs reading h(slot) MALL-direct
  auto h_mfmas = [&](int slot) {
    const unsigned short* hp = hbuf + slot * (BQ * HH);
    #pragma unroll
    for (int ks = 16; ks < 32; ++ks) {
      const int off = ((ks - 16) << 5) + (q << 3);
      bf16x8 A = ld_bf16x8_mall(hp + bb * HH + off);
      bf16x8 Bf = *(const bf16x8*)(lWg + n16 * KGP + 768 + off);
      if (ks & 1) ax1 = mfma16(A, Bf, ax1); else ax0 = mfma16(A, Bf, ax0);
    }
  };
  // r-part: 8 MFMAs reading rbuf MALL-direct; then write gt
  auto r_mfmas = [&]() {
    #pragma unroll
    for (int ks = 32; ks < 40; ++ks) {
      const int off = ((ks - 32) << 5) + (q << 3);
      bf16x8 A = ld_bf16x8_mall(rbuf + bb * (RH * NC) + off);
      bf16x8 Bf = *(const bf16x8*)(lWg + n16 * KGP + 512 + off);
      if (ks & 1) ax1 = mfma16(A, Bf, ax1); else ax0 = mfma16(A, Bf, ax0);
    }
    const int gcol = ((n16 >> 2) << 9) + j0 + (n16 & 3);
    const float bias = b_lstm[gcol];
    #pragma unroll
    for (int j = 0; j < 4; ++j)
      gt[(((wv & 1) << 4) + (q << 2) + j) * 17 + n16] = ax0[j] + ax1[j] + bias;
  };
  // y(t-1): waves 2,3 of y-blocks; needs h(t-1) and r(t-1)
  auto do_y = [&](int t) {
    const unsigned short* hp = hbuf + ((t + 1) & 1) * (BQ * HH);
    const int mt = wv - 2;
    const int bby = (mt << 4) + n16;
    f32x4 a0 = {0.f, 0.f, 0.f, 0.f}, a1 = {0.f, 0.f, 0.f, 0.f};
    #pragma unroll
    for (int ks = 0; ks < 24; ++ks) {
      const int kq = (ks << 5) + (q << 3);
      bf16x8 A = (ks < 16) ? ld_bf16x8_mall(hp + bby * HH + kq)
                           : ld_bf16x8_mall(rbuf + bby * (RH * NC) + (kq - 512));
      bf16x8 Bf = *(const bf16x8*)(lWo + n16 * WOP + kq);
      if (ks & 1) a1 = mfma16(A, Bf, a1); else a0 = mfma16(A, Bf, a0);
    }
    const int col = ((blk - 64) << 4) + n16;
    const float bias = b_out[col];
    #pragma unroll
    for (int j = 0; j < 4; ++j) {
      int row = (mt << 4) + (q << 2) + j;
      float y = a0[j] + a1[j] + bias;
      y = fminf(fmaxf(y, -CLIPV), CLIPV);
      out[(size_t)row * (TT * HH) + (size_t)(t - 1) * HH + col] = y;
    }
  };

  // pre-loop: wait all prepass, then x-part(0). h(-1)=0, r(-1)=0.
  wait_cnt(hdone, 128u);
  if (wv < 2) x_mfmas(0);

  for (int t = 0; t < TT; ++t) {
    unsigned short* hcur = hbuf + (t & 1) * (BQ * HH);

    if (t > 0) wait_cnt(rdone, 32u * (unsigned)t);  // r(t-1) (t=0: zeros)
    if (wv < 2) {
      r_mfmas();                          // gates(t) complete -> gt
    } else if (is_y && t > 0) {
      do_y(t);                            // y(t-1): h(t-1), r(t-1)
    }
    __syncthreads();
    if (tid < BQ) {                       // LSTM: batch=tid, 4 h-cols
      const int b = tid;
      u64 hv = 0;
      #pragma unroll
      for (int i = 0; i < 4; ++i) {
        float g_i = gt[b * 17 + i],     g_f = gt[b * 17 + 4 + i];
        float g_g = gt[b * 17 + 8 + i], g_o = gt[b * 17 + 12 + i];
        float c = cst[b * 4 + i];
        c = sigf(g_f) * c + sigf(g_i) * tanhf(g_g);
        float h = sigf(g_o) * tanhf(c);
        cst[b * 4 + i] = c;
        hv |= (u64)f2b(h) << (16 * i);
      }
      if (hbufD)                          // DNC mailbox: lands earliest
        st_u64((u64*)(hbufD + (size_t)(t & 1) * (BQ * HH) + (size_t)b * HH + j0), hv);
      st_u64((u64*)(hcur + b * HH + j0), hv);
    }
    __syncthreads();                      // drain h stores to MALL
    if (tid == 0) add_flag(hdone);        // h(t) published

    if (is_dnc) {
      // ---------------- phase C(t) ----------------
      if (hbufD) {
        if (wv >= 2) {                    // waves 2,3: destructive mailbox read
          const int g = tid - 128;        // 0..127 -> h cols 4g..4g+3
          u64* mb = (u64*)(hbufD + (size_t)(t & 1) * (BQ * HH) + (size_t)blk * HH) + g;
          u64 hv = ld_u64(mb);
          while (hv == ~0ull) { hv = ld_u64(mb); }
          st_u64(mb, ~0ull);              // re-arm sentinel (drained at B1)
          #pragma unroll
          for (int i = 0; i < 4; ++i)
            hlb[g * 4 + i] = __builtin_bit_cast(__bf16, (unsigned short)(hv >> (16 * i)));
        }
      } else {
        wait_cnt(hdone, 128u * (unsigned)(t + 2));  // fallback: full h(t)
        if (tid < 128) {
          u64 hv = ld_u64((const u64*)(hcur + blk * HH + tid * 4));
          #pragma unroll
          for (int i = 0; i < 4; ++i)
            hlb[tid * 4 + i] = __builtin_bit_cast(__bf16, (unsigned short)(hv >> (16 * i)));
        }
      }
      __syncthreads();                    // B1: h in LDS
      // xi = h @ W_xi + b_xi via MFMA (fragment-ordered wxbT: coalesced)
      {
        constexpr int TPW = 8;
        f32x4 acc[TPW];
        #pragma unroll
        for (int i = 0; i < TPW; ++i) acc[i] = f32x4{0.f, 0.f, 0.f, 0.f};
        const int ct0 = wv * TPW;
        const int ntile = (ct0 + TPW <= 30) ? TPW : (30 - ct0);
        for (int kt = 0; kt < 16; ++kt) {
          bf16x8 Bf = {};
          if (n16 == 0) Bf = *(const bf16x8*)(hlb + kt * 32 + (q << 3));
          if (wxbT) {
            #pragma unroll
            for (int i = 0; i < TPW; ++i) {
              if (i < ntile) {
                const __bf16* ap = wxbT
                    + (((size_t)(ct0 + i) * 16 + kt) << 9) + (lane << 3);
                acc[i] = mfma16(*(const bf16x8*)ap, Bf, acc[i]);
              }
            }
          } else {
            #pragma unroll
            for (int i = 0; i < TPW; ++i) {
              if (i < ntile) {
                const int col = (ct0 + i) * 16 + n16;
                bf16x8 Af;
                #pragma unroll
                for (int j = 0; j < 8; ++j)
                  Af[j] = (col < XI) ? (__bf16)W_xi[(size_t)(kt * 32 + (q << 3) + j) * XI + col]
                                     : (__bf16)0.0f;
                acc[i] = mfma16(Af, Bf, acc[i]);
              }
            }
          }
        }
        if (n16 == 0) {
          const int rowb = (lane >> 4) * 4;
          #pragma unroll
          for (int i = 0; i < TPW; ++i) {
            if (i < ntile) {
              #pragma unroll
              for (int j = 0; j < 4; ++j) {
                int col = (ct0 + i) * 16 + rowb + j;
                if (col < XI) xir[col] = acc[i][j] + b_xi[col];
              }
            }
          }
        }
      }
      __syncthreads();
      if (tid == 0) {
        scal[0] = 1.0f + softplusf(xir[324]);   // beta_w
        scal[1] = sigf(xir[457]);               // g_a
        scal[2] = sigf(xir[458]);               // g_w
      }
      if (tid >= 4 && tid < 8) {
        int r = tid - 4;
        scal[4 + r]  = 1.0f + softplusf(xir[256 + r]);  // beta_r
        scal[12 + r] = sigf(xir[453 + r]);              // free
        float p0 = xir[459 + r * 3], p1 = xir[460 + r * 3], p2 = xir[461 + r * 3];
        float m = fmaxf(p0, fmaxf(p1, p2));
        float e0 = expf(p0 - m), e1 = expf(p1 - m), e2 = expf(p2 - m);
        float s = e0 + e1 + e2;
        scal[16 + r * 3 + 0] = e0 / s;
        scal[16 + r * 3 + 1] = e1 / s;
        scal[16 + r * 3 + 2] = e2 / s;
      }
      if (tid >= 64 && tid < 128) er[tid - 64] = sigf(xir[325 + (tid - 64)]);
      __syncthreads();
      // -- old norms / write-key sim / usage + stable sort + allocation
      if (wv == 0) {
        float s = 0.f;
        for (int w = 0; w < 64; ++w) { float m = Ml[lane * 65 + w]; s += m * m; }
        nrmo[lane] = sqrtf(s) + EPSV;
      } else if (wv == 1) {
        float d = 0.f;
        for (int w = 0; w < 64; ++w) d += Ml[lane * 65 + w] * xir[260 + w];
        simw[lane] = d;
        float v = xir[260 + lane];
        float s2 = wsum(v * v);
        if (lane == 0) scal[3] = sqrtf(s2) + EPSV;
      } else if (wv == 2) {
        float psi = 1.f;
        #pragma unroll
        for (int r = 0; r < 4; ++r) psi *= (1.f - scal[12 + r] * wrl[r * 64 + lane]);
        float un = uu[lane], w_ = wwl[lane];
        un = (un + w_ - un * w_) * psi;
        uu[lane] = un;
        // stable bitonic argsort ascending by (u, index)
        float v = un; int id = lane;
        for (int k = 2; k <= 64; k <<= 1) {
          for (int j2 = k >> 1; j2 > 0; j2 >>= 1) {
            float ov = __shfl_xor(v, j2, 64);
            int   oi = __shfl_xor(id, j2, 64);
            bool up    = ((lane & k) == 0);
            bool lower = ((lane & j2) == 0);
            bool lt = (v < ov) || (v == ov && id < oi);
            bool keep = (lower == up) ? lt : !lt;
            if (!keep) { v = ov; id = oi; }
          }
        }
        float cp = v;
        for (int d2 = 1; d2 < 64; d2 <<= 1) {
          float o = __shfl_up(cp, d2, 64);
          if (lane >= d2) cp *= o;
        }
        float pe = __shfl_up(cp, 1, 64);
        if (lane == 0) pe = 1.0f;
        aas[id] = (1.0f - v) * pe;
      }
      __syncthreads();
      // -- write content weights -> ww
      if (wv == 0) {
        float x = simw[lane] / (nrmo[lane] * scal[3]) * scal[0];
        float mx = wmaxr(x);
        float e = expf(x - mx);
        float s = wsum(e);
        float cw = e / s;
        wwl[lane] = scal[2] * (scal[1] * aas[lane] + (1.f - scal[1]) * cw);
      }
      __syncthreads();
      // -- M and L updates (old p)
      {
        const int n = tid >> 2, c4 = (tid & 3) << 4;
        float wwn = wwl[n];
        #pragma unroll
        for (int w = 0; w < 16; ++w) {
          int wj = c4 + w;
          Ml[n * 65 + wj] = Ml[n * 65 + wj] * (1.f - wwn * er[wj]) + wwn * xir[389 + wj];
        }
        #pragma unroll
        for (int w = 0; w < 16; ++w) {
          int m2 = c4 + w;
          float Lv = (n == m2) ? 0.f
                   : ((1.f - wwn - wwl[m2]) * Ll[n * 65 + m2] + wwn * pp[m2]);
          Ll[n * 65 + m2] = Lv;
        }
      }
      __syncthreads();
      // -- fwd/bwd (old wr, new L), read-key sims (new M), new norms
      {
        float f = 0.f, bw2 = 0.f, d = 0.f;
        for (int m2 = 0; m2 < 64; ++m2) {
          float wrm = wrl[wv * 64 + m2];
          f   += Ll[lane * 65 + m2] * wrm;
          bw2 += Ll[m2 * 65 + lane] * wrm;
        }
        fwd[wv * 64 + lane] = f;
        bwd[wv * 64 + lane] = bw2;
        for (int w = 0; w < 64; ++w) d += Ml[lane * 65 + w] * xir[wv * 64 + w];
        simr[wv * 64 + lane] = d;
        float v = xir[wv * 64 + lane];
        float s2 = wsum(v * v);
        if (lane == 0) scal[8 + wv] = sqrtf(s2) + EPSV;
        if (wv == 0) {
          float s = 0.f;
          for (int w = 0; w < 64; ++w) { float m = Ml[lane * 65 + w]; s += m * m; }
          nrmn[lane] = sqrtf(s) + EPSV;
        }
      }
      __syncthreads();
      // -- read content weights, new wr, p update
      {
        float x = simr[wv * 64 + lane] / (nrmn[lane] * scal[8 + wv]) * scal[4 + wv];
        float mx = wmaxr(x);
        float e = expf(x - mx);
        float s = wsum(e);
        float cw = e / s;
        float wrn = scal[16 + wv * 3 + 0] * bwd[wv * 64 + lane]
                  + scal[16 + wv * 3 + 1] * cw
                  + scal[16 + wv * 3 + 2] * fwd[wv * 64 + lane];
        wrl[wv * 64 + lane] = wrn;
        if (wv == 3) {
          float s3 = wsum(wwl[lane]);
          pp[lane] = (1.f - s3) * pp[lane] + wwl[lane];
        }
      }
      __syncthreads();
      // -- r(t) = wr @ M -> rbuf (bf16 packed, MALL write-through)
      {
        float rv = 0.f;
        for (int n2 = 0; n2 < 64; ++n2) rv += wrl[wv * 64 + n2] * Ml[n2 * 65 + lane];
        unsigned v0 = f2b(rv);
        unsigned v1 = __shfl_down(v0, 1, 64);
        unsigned v2 = __shfl_down(v0, 2, 64);
        unsigned v3 = __shfl_down(v0, 3, 64);
        if ((lane & 3) == 0) {
          u64 pk = (u64)v0 | ((u64)v1 << 16) | ((u64)v2 << 32) | ((u64)v3 << 48);
          st_u64((u64*)(rbuf + blk * (RH * NC) + wv * 64 + lane), pk);
        }
      }
      __syncthreads();                    // drain r stores
      if (tid == 0) add_flag(rdone);      // r(t) published
      // gates x/h parts for t+1 (after r publication -- off critical path)
      if (t < TT - 1) {
        if (hbufD) wait_cnt(hdone, 128u * (unsigned)(t + 2));  // hbuf ready
        if (wv < 2) {
          ax0 = f32x4{0.f, 0.f, 0.f, 0.f};
          ax1 = f32x4{0.f, 0.f, 0.f, 0.f};
          x_mfmas(t + 1);
          h_mfmas(t & 1);
        }
      }
    } else {
      // overlap DNC phase C with x-part(t+1); then wait h and do h-part
      if (wv < 2 && t < TT - 1) {
        ax0 = f32x4{0.f, 0.f, 0.f, 0.f};
        ax1 = f32x4{0.f, 0.f, 0.f, 0.f};
        x_mfmas(t + 1);
      }
      wait_cnt(hdone, 128u * (unsigned)(t + 2));
      if (wv < 2 && t < TT - 1) h_mfmas(t & 1);
    }
  }

  // final y(TT-1): needs r(TT-1)
  if (is_y) {
    wait_cnt(rdone, 32u * (unsigned)TT);
    if (wv >= 2) do_y(TT);
  }
}

extern "C" void kernel_launch(void* const* d_in, const int* in_sizes, int n_in,
                              void* d_out, int out_size, void* d_ws, size_t ws_size,
                              hipStream_t stream) {
  const int*   src    = (const int*)d_in[0];
  const float* emb    = (const float*)d_in[2];
  const float* Wih    = (const float*)d_in[3];
  const float* Whh    = (const float*)d_in[4];
  const float* b_lstm = (const float*)d_in[5];
  const float* W_xi   = (const float*)d_in[6];
  const float* b_xi   = (const float*)d_in[7];
  const float* W_out  = (const float*)d_in[8];
  const float* b_out  = (const float*)d_in[9];
  float* out = (float*)d_out;

  char* ws = (char*)d_ws;
  unsigned*       hdone  = (unsigned*)(ws + WS_HFLG);
  unsigned*       rdone  = (unsigned*)(ws + WS_RFLG);
  unsigned short* hbuf   = (unsigned short*)(ws + WS_HBUF);
  unsigned short* rbuf   = (unsigned short*)(ws + WS_RBUF);
  unsigned short* wxbT   = (ws_size >= WS_MIN)   ? (unsigned short*)(ws + WS_WXBT)  : nullptr;
  unsigned short* embbuf = (ws_size >= WS_FULL)  ? (unsigned short*)(ws + WS_EMB)   : nullptr;
  unsigned short* hbufD  = (ws_size >= WS_FULL2) ? (unsigned short*)(ws + WS_HBUFD) : nullptr;

  hipMemsetAsync(d_ws, 0, WS_ZERO, stream);   // counters + h0 + r0
  if (hbufD)
    hipMemsetAsync(ws + WS_HBUFD, 0xFF, HBUFD_BYTES, stream);  // mailbox sentinels
  hipFuncSetAttribute((const void*)dnc_kernel,
                      hipFuncAttributeMaxDynamicSharedMemorySize, SMEM_BYTES);
  dnc_kernel<<<dim3(NBLK), dim3(BS), SMEM_BYTES, stream>>>(
      src, emb, Wih, Whh, b_lstm, W_xi, b_xi, W_out, b_out, out,
      hdone, rdone, hbuf, rbuf, wxbT, embbuf, hbufD);
}

// Round 13
// 7945.786 us; speedup vs baseline: 7.9493x; 1.3552x over previous
//
#include <hip/hip_runtime.h>

// Persistent-grid DNC encoder for MI355X (gfx950).
// R17 = R16 (10.77 ms) + xi OFFLOAD. R14/R15 probes: xi = 22.7us of the
// 44us step; R16's coalescing won only ~2us -> xi is bound by per-CU L1
// line throughput (each DNC block streamed ALL 491KB of W_xi = 8192 lines
// per step through one CU). Fix: blocks 96..125 waves 2,3 become helpers;
// helper ct computes xi cols 16ct..16ct+15 for ALL 32 batches (A = h rows
// MALL-direct prefetched 8-deep, B = 16KB fragment-ordered wxbT slice,
// L1-RESIDENT across steps), +bias, publishes 32x16 f32 to xibuf (reuses
// retired mailbox 64KB) and bumps xdone (+1/wave, target 60(t+1)). DNC
// blocks never touch W_xi/h: wait xdone, load 480-f32 xi row (240 u64
// lanes), interior unchanged. Same kt-order MFMA chain + identical
// fragment values -> bit-identical xir. Helper wait_cnt moved before its
// gates prefetch so h-detection is immediate.

constexpr int NBLK = 128;
constexpr int BS   = 256;
constexpr int BQ   = 32;
constexpr int TT   = 256;
constexpr int HH   = 512;
constexpr int RH   = 4;
constexpr int NC   = 64;
constexpr int XI   = 471;
constexpr int KG   = 1280;    // gates K = 512(x)+256(r)+512(h)
constexpr int KGP  = 1288;    // padded LDS K stride (bf16)
constexpr int WOP  = 776;     // padded W_out K stride
constexpr float CLIPV = 50000.0f;
constexpr float EPSV  = 1e-6f;

typedef __bf16 bf16x8 __attribute__((ext_vector_type(8)));
typedef float  f32x4  __attribute__((ext_vector_type(4)));
typedef unsigned long long u64;

// ---- LDS layout (bytes) ----
constexpr int OFF_WG   = 0;                      // 16*KGP bf16 = 41216
constexpr int OFF_WO   = OFF_WG  + 16*KGP*2;     // 16*WOP bf16 = 24832
constexpr int OFF_GT   = OFF_WO  + 16*WOP*2;     // 32*17 f32   = 2176
constexpr int OFF_CST  = OFF_GT  + 32*17*4;      // 128 f32     = 512
constexpr int OFF_HLB  = OFF_CST + 512;          // 512 bf16    = 1024
constexpr int OFF_DNC  = OFF_HLB + 1024;
constexpr int D_M    = 0;                        // 64*65 f32
constexpr int D_L    = D_M   + 64*65*4;
constexpr int D_XIR  = D_L   + 64*65*4;          // 480 f32
constexpr int D_WR   = D_XIR + 480*4;
constexpr int D_FWD  = D_WR  + 256*4;
constexpr int D_BWD  = D_FWD + 256*4;
constexpr int D_SIMR = D_BWD + 256*4;
constexpr int D_VEC  = D_SIMR+ 256*4;            // 8 arrays of 64 f32
constexpr int D_SCAL = D_VEC + 8*64*4;           // 32 f32
constexpr int SMEM_BYTES = OFF_DNC + D_SCAL + 32*4;   // 111232

// ---- workspace layout (bytes) ----
constexpr size_t WS_HFLG  = 0;                         // hdone counter line
constexpr size_t WS_XDONE = 128;                       // xdone counter line
constexpr size_t WS_RFLG  = 8192;                      // rdone counter line
constexpr size_t WS_HBUF  = 8192 + 2048;               // 2*32*512 bf16 = 65536
constexpr size_t WS_RBUF  = WS_HBUF + 65536;           // 32*256 bf16   = 16384
constexpr size_t WS_WXBT  = WS_RBUF + 16384;           // 480*512 bf16  = 491520
constexpr size_t WS_EMB   = WS_WXBT + 491520;          // 8192*512 bf16 = 8388608
constexpr size_t WS_MIN   = WS_WXBT + 491520;
constexpr size_t WS_FULL  = WS_EMB + 8388608;
constexpr size_t WS_XIB   = WS_FULL;                   // 32*512 f32 = 65536
constexpr size_t XIB_BYTES = 32ull * 512 * 4;
constexpr size_t WS_FULL2 = WS_XIB + XIB_BYTES;
constexpr size_t WS_ZERO  = WS_RBUF + 16384;           // counters + hbuf + rbuf

__device__ __forceinline__ unsigned short f2b(float f) {
  unsigned u = __builtin_bit_cast(unsigned, f);
  u += 0x7fffu + ((u >> 16) & 1u);
  return (unsigned short)(u >> 16);
}
__device__ __forceinline__ float sigf(float x) { return 1.0f / (1.0f + expf(-x)); }
__device__ __forceinline__ float softplusf(float x) { return (x > 20.0f) ? x : log1pf(expf(x)); }
__device__ __forceinline__ float wsum(float v) {
  #pragma unroll
  for (int o = 32; o; o >>= 1) v += __shfl_xor(v, o, 64);
  return v;
}
__device__ __forceinline__ float wmaxr(float v) {
  #pragma unroll
  for (int o = 32; o; o >>= 1) v = fmaxf(v, __shfl_xor(v, o, 64));
  return v;
}
__device__ __forceinline__ f32x4 mfma16(bf16x8 a, bf16x8 b, f32x4 c) {
  return __builtin_amdgcn_mfma_f32_16x16x32_bf16(a, b, c, 0, 0, 0);
}
__device__ __forceinline__ void drain_vm() {
  asm volatile("s_waitcnt vmcnt(0)" ::: "memory");
}

// MALL write-through / MALL-direct (relaxed agent atomics)
__device__ __forceinline__ void st_u64(u64* p, u64 v) {
  __hip_atomic_store(p, v, __ATOMIC_RELAXED, __HIP_MEMORY_SCOPE_AGENT);
}
__device__ __forceinline__ u64 ld_u64(const u64* p) {
  return __hip_atomic_load(p, __ATOMIC_RELAXED, __HIP_MEMORY_SCOPE_AGENT);
}
__device__ __forceinline__ unsigned ld_flag(const unsigned* p) {
  return __hip_atomic_load(p, __ATOMIC_RELAXED, __HIP_MEMORY_SCOPE_AGENT);
}
__device__ __forceinline__ void add_flag(unsigned* p) {
  __hip_atomic_fetch_add(p, 1u, __ATOMIC_RELAXED, __HIP_MEMORY_SCOPE_AGENT);
}
struct alignas(16) U64x2 { u64 a, b; };
__device__ __forceinline__ bf16x8 ld_bf16x8_mall(const unsigned short* p) {
  U64x2 v;
  v.a = ld_u64((const u64*)p);
  v.b = ld_u64((const u64*)p + 1);
  return __builtin_bit_cast(bf16x8, v);
}

// wave 0 polls a single shared counter (one request per round), block release
__device__ __forceinline__ void wait_cnt(const unsigned* cnt, unsigned target) {
  if ((threadIdx.x >> 6) == 0) {
    while (ld_flag(cnt) < target) { /* tight spin, single line */ }
  }
  __builtin_amdgcn_fence(__ATOMIC_ACQUIRE, "workgroup");
  __syncthreads();
}

__global__ __launch_bounds__(BS, 1) void dnc_kernel(
    const int* __restrict__ src, const float* __restrict__ emb,
    const float* __restrict__ Wih, const float* __restrict__ Whh,
    const float* __restrict__ b_lstm, const float* __restrict__ W_xi,
    const float* __restrict__ b_xi, const float* __restrict__ W_out,
    const float* __restrict__ b_out, float* __restrict__ out,
    unsigned* __restrict__ hdone, unsigned* __restrict__ rdone,
    unsigned* __restrict__ xdone,
    unsigned short* __restrict__ hbuf, unsigned short* __restrict__ rbuf,
    unsigned short* __restrict__ wxbT_, unsigned short* __restrict__ embbuf_,
    float* __restrict__ xibuf)
{
  extern __shared__ char smem[];
  __bf16* lWg  = (__bf16*)(smem + OFF_WG);
  __bf16* lWo  = (__bf16*)(smem + OFF_WO);
  float*  gt   = (float*)(smem + OFF_GT);
  float*  cst  = (float*)(smem + OFF_CST);
  __bf16* hlb  = (__bf16*)(smem + OFF_HLB);
  char*   dnc  = smem + OFF_DNC;
  float* Ml   = (float*)(dnc + D_M);
  float* Ll   = (float*)(dnc + D_L);
  float* xir  = (float*)(dnc + D_XIR);
  float* wrl  = (float*)(dnc + D_WR);
  float* fwd  = (float*)(dnc + D_FWD);
  float* bwd  = (float*)(dnc + D_BWD);
  float* simr = (float*)(dnc + D_SIMR);
  float* uu   = (float*)(dnc + D_VEC);
  float* pp   = uu + 64;
  float* wwl  = uu + 128;
  float* aas  = uu + 192;
  float* nrmo = uu + 256;
  float* nrmn = uu + 320;
  float* simw = uu + 384;
  float* er   = uu + 448;
  float* scal = (float*)(dnc + D_SCAL);
  // scal: [0]beta_w [1]g_a [2]g_w [3]wknrm [4..7]beta_r [8..11]rkn [12..15]free [16..27]pi

  const int tid  = threadIdx.x;
  const int blk  = blockIdx.x;
  const int lane = tid & 63;
  const int wv   = tid >> 6;
  const int q    = lane >> 4;
  const int n16  = lane & 15;
  const int j0   = blk << 2;    // h slice: columns j0..j0+3
  const __bf16* wxbT = (const __bf16*)wxbT_;
  const __bf16* embbuf = (const __bf16*)embbuf_;
  const bool is_dnc = (blk < BQ);
  const bool is_y   = (blk >= 64 && blk < 96);
  const bool is_xi  = (blk >= 96 && blk < 126) && (xibuf != nullptr) && (wxbT_ != nullptr);

  // ---------------- prepass ----------------
  for (int e = tid; e < 16 * KG; e += BS) {
    int k = e >> 4, cc = e & 15;
    int gcol = ((cc >> 2) << 9) + j0 + (cc & 3);   // gate*512 + h-col
    float w = (k < 768) ? Wih[k * 2048 + gcol] : Whh[(k - 768) * 2048 + gcol];
    lWg[cc * KGP + k] = (__bf16)w;
  }
  if (is_y) {
    for (int e = tid; e < 16 * 768; e += BS) {
      int k = e >> 4, cc = e & 15;
      int col = ((blk - 64) << 4) + cc;
      lWo[cc * WOP + k] = (__bf16)W_out[k * HH + col];
    }
  }
  if (wxbT_) {
    // W_xi -> bf16 in MFMA-FRAGMENT order (coalesced, L1-resident slices):
    // element e = ((tile*16 + kt)*64 + lane)*8 + j
    //   col = tile*16 + (lane&15)          (0 pad for col >= XI)
    //   k   = kt*32 + (lane>>4)*8 + j
    for (int w = blk * BS + tid; w < 61440; w += NBLK * BS) {
      int e = w << 2;
      int jb    = e & 7;
      int lane_ = (e >> 3) & 63;
      int f     = e >> 9;              // tile*16 + kt
      int col   = (f >> 4) * 16 + (lane_ & 15);
      int k0    = (f & 15) * 32 + (lane_ >> 4) * 8 + jb;
      u64 pk = 0;
      if (col < XI) {
        #pragma unroll
        for (int j = 0; j < 4; ++j) {
          unsigned short us = f2b(W_xi[(size_t)(k0 + j) * XI + col]);
          pk |= (u64)us << (16 * j);
        }
      }
      st_u64((u64*)wxbT_ + w, pk);
    }
  }
  if (embbuf_) { // gather emb[src] -> bf16 (MALL write-through)
    for (int rr = blk * 2 + (tid >> 7); rr < BQ * TT; rr += NBLK * 2) {
      const int t128 = tid & 127;
      const float* s = emb + (size_t)src[rr] * HH;
      float4 v = *(const float4*)(s + t128 * 4);
      u64 pk = (u64)f2b(v.x) | ((u64)f2b(v.y) << 16)
             | ((u64)f2b(v.z) << 32) | ((u64)f2b(v.w) << 48);
      st_u64((u64*)(embbuf_ + (size_t)rr * HH + t128 * 4), pk);
    }
  }
  if (tid < 128) cst[tid] = 0.0f;
  if (is_dnc) {
    for (int e = tid; e < 64 * 65; e += BS) { Ml[e] = 0.0f; Ll[e] = 0.0f; }
    if (tid < 64) { uu[tid] = 0.0f; pp[tid] = 0.0f; wwl[tid] = 0.0f; }
    wrl[tid] = 0.0f;
  }
  __syncthreads();
  if (tid == 0) add_flag(hdone);        // prepass published (+1 of 128)

  // persistent gates accumulators (waves 0,1)
  f32x4 ax0 = {0.f, 0.f, 0.f, 0.f}, ax1 = {0.f, 0.f, 0.f, 0.f};
  const int bb = ((wv & 1) << 4) + n16;          // gates A-row (waves 0,1)

  // x-part: 16 MFMAs (embedding of step tt)
  auto x_mfmas = [&](int tt) {
    const __bf16* eb = embbuf ? (embbuf + ((size_t)bb * TT + tt) * HH) : nullptr;
    const float* ep = embbuf ? nullptr
                             : (emb + (size_t)src[bb * TT + tt] * HH + (q << 3));
    #pragma unroll
    for (int ks = 0; ks < 16; ++ks) {
      const int kq = (ks << 5) + (q << 3);
      bf16x8 A;
      if (eb) {
        A = *(const bf16x8*)(eb + kq);
      } else {
        const float* p = ep + (ks << 5);
        #pragma unroll
        for (int j = 0; j < 8; ++j) A[j] = (__bf16)p[j];
      }
      bf16x8 Bf = *(const bf16x8*)(lWg + n16 * KGP + kq);
      if (ks & 1) ax1 = mfma16(A, Bf, ax1); else ax0 = mfma16(A, Bf, ax0);
    }
  };
  // h-part: 16 MFMAs reading h(slot) MALL-direct
  auto h_mfmas = [&](int slot) {
    const unsigned short* hp = hbuf + slot * (BQ * HH);
    #pragma unroll
    for (int ks = 16; ks < 32; ++ks) {
      const int off = ((ks - 16) << 5) + (q << 3);
      bf16x8 A = ld_bf16x8_mall(hp + bb * HH + off);
      bf16x8 Bf = *(const bf16x8*)(lWg + n16 * KGP + 768 + off);
      if (ks & 1) ax1 = mfma16(A, Bf, ax1); else ax0 = mfma16(A, Bf, ax0);
    }
  };
  // r-part: 8 MFMAs reading rbuf MALL-direct; then write gt
  auto r_mfmas = [&]() {
    #pragma unroll
    for (int ks = 32; ks < 40; ++ks) {
      const int off = ((ks - 32) << 5) + (q << 3);
      bf16x8 A = ld_bf16x8_mall(rbuf + bb * (RH * NC) + off);
      bf16x8 Bf = *(const bf16x8*)(lWg + n16 * KGP + 512 + off);
      if (ks & 1) ax1 = mfma16(A, Bf, ax1); else ax0 = mfma16(A, Bf, ax0);
    }
    const int gcol = ((n16 >> 2) << 9) + j0 + (n16 & 3);
    const float bias = b_lstm[gcol];
    #pragma unroll
    for (int j = 0; j < 4; ++j)
      gt[(((wv & 1) << 4) + (q << 2) + j) * 17 + n16] = ax0[j] + ax1[j] + bias;
  };
  // y(t-1): waves 2,3 of y-blocks; needs h(t-1) and r(t-1)
  auto do_y = [&](int t) {
    const unsigned short* hp = hbuf + ((t + 1) & 1) * (BQ * HH);
    const int mt = wv - 2;
    const int bby = (mt << 4) + n16;
    f32x4 a0 = {0.f, 0.f, 0.f, 0.f}, a1 = {0.f, 0.f, 0.f, 0.f};
    #pragma unroll
    for (int ks = 0; ks < 24; ++ks) {
      const int kq = (ks << 5) + (q << 3);
      bf16x8 A = (ks < 16) ? ld_bf16x8_mall(hp + bby * HH + kq)
                           : ld_bf16x8_mall(rbuf + bby * (RH * NC) + (kq - 512));
      bf16x8 Bf = *(const bf16x8*)(lWo + n16 * WOP + kq);
      if (ks & 1) a1 = mfma16(A, Bf, a1); else a0 = mfma16(A, Bf, a0);
    }
    const int col = ((blk - 64) << 4) + n16;
    const float bias = b_out[col];
    #pragma unroll
    for (int j = 0; j < 4; ++j) {
      int row = (mt << 4) + (q << 2) + j;
      float y = a0[j] + a1[j] + bias;
      y = fminf(fmaxf(y, -CLIPV), CLIPV);
      out[(size_t)row * (TT * HH) + (size_t)(t - 1) * HH + col] = y;
    }
  };
  // xi helper (blocks 96..125, waves 2,3): cols 16ct..16ct+15, all 32 batches
  auto do_xi = [&](int t) {
    const unsigned short* hp = hbuf + (t & 1) * (BQ * HH)
                             + (size_t)((((wv - 2) << 4) + n16) * HH) + (q << 3);
    const int ct = blk - 96;
    f32x4 acc = {0.f, 0.f, 0.f, 0.f};
    bf16x8 A[8];
    #pragma unroll
    for (int kt = 0; kt < 8; ++kt) A[kt] = ld_bf16x8_mall(hp + (kt << 5));
    #pragma unroll
    for (int kt = 0; kt < 8; ++kt) {
      bf16x8 Bf = *(const bf16x8*)(wxbT + (((size_t)(ct << 4) + kt) << 9) + (lane << 3));
      acc = mfma16(A[kt], Bf, acc);
    }
    #pragma unroll
    for (int kt = 0; kt < 8; ++kt) A[kt] = ld_bf16x8_mall(hp + ((8 + kt) << 5));
    #pragma unroll
    for (int kt = 0; kt < 8; ++kt) {
      bf16x8 Bf = *(const bf16x8*)(wxbT + (((size_t)(ct << 4) + 8 + kt) << 9) + (lane << 3));
      acc = mfma16(A[kt], Bf, acc);
    }
    const int col = (ct << 4) + n16;
    const float bias = b_xi[col];
    #pragma unroll
    for (int j = 0; j < 4; ++j) {
      float v = acc[j] + bias;
      unsigned lo = __builtin_bit_cast(unsigned, v);
      unsigned hi = __shfl_down(lo, 1, 64);
      if (!(n16 & 1)) {
        int batch = ((wv - 2) << 4) + (q << 2) + j;
        st_u64((u64*)(xibuf + ((size_t)batch << 9) + col),
               (u64)lo | ((u64)hi << 32));
      }
    }
    drain_vm();
    if (lane == 0) add_flag(xdone);     // +1 per wave -> 60 per step
  };

  // pre-loop: wait all prepass, then x-part(0). h(-1)=0, r(-1)=0.
  wait_cnt(hdone, 128u);
  if (wv < 2) x_mfmas(0);

  for (int t = 0; t < TT; ++t) {
    unsigned short* hcur = hbuf + (t & 1) * (BQ * HH);

    if (t > 0) wait_cnt(rdone, 32u * (unsigned)t);  // r(t-1) (t=0: zeros)
    if (wv < 2) {
      r_mfmas();                          // gates(t) complete -> gt
    } else if (is_y && t > 0) {
      do_y(t);                            // y(t-1): h(t-1), r(t-1)
    }
    __syncthreads();
    if (tid < BQ) {                       // LSTM: batch=tid, 4 h-cols
      const int b = tid;
      u64 hv = 0;
      #pragma unroll
      for (int i = 0; i < 4; ++i) {
        float g_i = gt[b * 17 + i],     g_f = gt[b * 17 + 4 + i];
        float g_g = gt[b * 17 + 8 + i], g_o = gt[b * 17 + 12 + i];
        float c = cst[b * 4 + i];
        c = sigf(g_f) * c + sigf(g_i) * tanhf(g_g);
        float h = sigf(g_o) * tanhf(c);
        cst[b * 4 + i] = c;
        hv |= (u64)f2b(h) << (16 * i);
      }
      st_u64((u64*)(hcur + b * HH + j0), hv);
    }
    __syncthreads();                      // drain h stores to MALL
    if (tid == 0) add_flag(hdone);        // h(t) published

    if (!is_dnc) {
      if (is_xi) {
        // helpers: detect h(t) immediately, then xi; gates prefetch after
        wait_cnt(hdone, 128u * (unsigned)(t + 2));
        if (wv >= 2) {
          do_xi(t);
        } else if (t < TT - 1) {
          ax0 = f32x4{0.f, 0.f, 0.f, 0.f};
          ax1 = f32x4{0.f, 0.f, 0.f, 0.f};
          x_mfmas(t + 1);
          h_mfmas(t & 1);
        }
      } else {
        if (wv < 2 && t < TT - 1) {
          ax0 = f32x4{0.f, 0.f, 0.f, 0.f};
          ax1 = f32x4{0.f, 0.f, 0.f, 0.f};
          x_mfmas(t + 1);
        }
        wait_cnt(hdone, 128u * (unsigned)(t + 2));
        if (wv < 2 && t < TT - 1) h_mfmas(t & 1);
      }
      continue;
    }

    // ---------------- DNC block: phase C(t) ----------------
    if (xibuf && wxbT_) {
      wait_cnt(xdone, 60u * (unsigned)(t + 1));   // xi(t) published
      if (tid < 240) {                            // 480 f32, coalesced u64
        u64 v = ld_u64((const u64*)(xibuf + ((size_t)blk << 9)) + tid);
        xir[tid * 2]     = __builtin_bit_cast(float, (unsigned)v);
        xir[tid * 2 + 1] = __builtin_bit_cast(float, (unsigned)(v >> 32));
      }
      __syncthreads();                            // xir ready
    } else {
      // fallback: in-block xi (R16 path)
      wait_cnt(hdone, 128u * (unsigned)(t + 2));
      if (tid < 128) {
        u64 hv = ld_u64((const u64*)(hcur + blk * HH + tid * 4));
        #pragma unroll
        for (int i = 0; i < 4; ++i)
          hlb[tid * 4 + i] = __builtin_bit_cast(__bf16, (unsigned short)(hv >> (16 * i)));
      }
      __syncthreads();
      {
        constexpr int TPW = 8;
        f32x4 acc[TPW];
        #pragma unroll
        for (int i = 0; i < TPW; ++i) acc[i] = f32x4{0.f, 0.f, 0.f, 0.f};
        const int ct0 = wv * TPW;
        const int ntile = (ct0 + TPW <= 30) ? TPW : (30 - ct0);
        for (int kt = 0; kt < 16; ++kt) {
          bf16x8 Bf = {};
          if (n16 == 0) Bf = *(const bf16x8*)(hlb + kt * 32 + (q << 3));
          if (wxbT) {
            #pragma unroll
            for (int i = 0; i < TPW; ++i) {
              if (i < ntile) {
                const __bf16* ap = wxbT
                    + (((size_t)(ct0 + i) * 16 + kt) << 9) + (lane << 3);
                acc[i] = mfma16(*(const bf16x8*)ap, Bf, acc[i]);
              }
            }
          } else {
            #pragma unroll
            for (int i = 0; i < TPW; ++i) {
              if (i < ntile) {
                const int col = (ct0 + i) * 16 + n16;
                bf16x8 Af;
                #pragma unroll
                for (int j = 0; j < 8; ++j)
                  Af[j] = (col < XI) ? (__bf16)W_xi[(size_t)(kt * 32 + (q << 3) + j) * XI + col]
                                     : (__bf16)0.0f;
                acc[i] = mfma16(Af, Bf, acc[i]);
              }
            }
          }
        }
        if (n16 == 0) {
          const int rowb = (lane >> 4) * 4;
          #pragma unroll
          for (int i = 0; i < TPW; ++i) {
            if (i < ntile) {
              #pragma unroll
              for (int j = 0; j < 4; ++j) {
                int col = (ct0 + i) * 16 + rowb + j;
                if (col < XI) xir[col] = acc[i][j] + b_xi[col];
              }
            }
          }
        }
      }
      __syncthreads();
    }
    // ---- scalars ----
    if (tid == 0) {
      scal[0] = 1.0f + softplusf(xir[324]);   // beta_w
      scal[1] = sigf(xir[457]);               // g_a
      scal[2] = sigf(xir[458]);               // g_w
    }
    if (tid >= 4 && tid < 8) {
      int r = tid - 4;
      scal[4 + r]  = 1.0f + softplusf(xir[256 + r]);  // beta_r
      scal[12 + r] = sigf(xir[453 + r]);              // free
      float p0 = xir[459 + r * 3], p1 = xir[460 + r * 3], p2 = xir[461 + r * 3];
      float m = fmaxf(p0, fmaxf(p1, p2));
      float e0 = expf(p0 - m), e1 = expf(p1 - m), e2 = expf(p2 - m);
      float s = e0 + e1 + e2;
      scal[16 + r * 3 + 0] = e0 / s;
      scal[16 + r * 3 + 1] = e1 / s;
      scal[16 + r * 3 + 2] = e2 / s;
    }
    if (tid >= 64 && tid < 128) er[tid - 64] = sigf(xir[325 + (tid - 64)]);
    __syncthreads();
    // -- old norms / write-key sim / usage + stable sort + allocation
    if (wv == 0) {
      float s = 0.f;
      for (int w = 0; w < 64; ++w) { float m = Ml[lane * 65 + w]; s += m * m; }
      nrmo[lane] = sqrtf(s) + EPSV;
    } else if (wv == 1) {
      float d = 0.f;
      for (int w = 0; w < 64; ++w) d += Ml[lane * 65 + w] * xir[260 + w];
      simw[lane] = d;
      float v = xir[260 + lane];
      float s2 = wsum(v * v);
      if (lane == 0) scal[3] = sqrtf(s2) + EPSV;
    } else if (wv == 2) {
      float psi = 1.f;
      #pragma unroll
      for (int r = 0; r < 4; ++r) psi *= (1.f - scal[12 + r] * wrl[r * 64 + lane]);
      float un = uu[lane], w_ = wwl[lane];
      un = (un + w_ - un * w_) * psi;
      uu[lane] = un;
      // stable bitonic argsort ascending by (u, index)
      float v = un; int id = lane;
      for (int k = 2; k <= 64; k <<= 1) {
        for (int j2 = k >> 1; j2 > 0; j2 >>= 1) {
          float ov = __shfl_xor(v, j2, 64);
          int   oi = __shfl_xor(id, j2, 64);
          bool up    = ((lane & k) == 0);
          bool lower = ((lane & j2) == 0);
          bool lt = (v < ov) || (v == ov && id < oi);
          bool keep = (lower == up) ? lt : !lt;
          if (!keep) { v = ov; id = oi; }
        }
      }
      float cp = v;
      for (int d2 = 1; d2 < 64; d2 <<= 1) {
        float o = __shfl_up(cp, d2, 64);
        if (lane >= d2) cp *= o;
      }
      float pe = __shfl_up(cp, 1, 64);
      if (lane == 0) pe = 1.0f;
      aas[id] = (1.0f - v) * pe;
    }
    __syncthreads();
    // -- write content weights -> ww
    if (wv == 0) {
      float x = simw[lane] / (nrmo[lane] * scal[3]) * scal[0];
      float mx = wmaxr(x);
      float e = expf(x - mx);
      float s = wsum(e);
      float cw = e / s;
      wwl[lane] = scal[2] * (scal[1] * aas[lane] + (1.f - scal[1]) * cw);
    }
    __syncthreads();
    // -- M and L updates (old p)
    {
      const int n = tid >> 2, c4 = (tid & 3) << 4;
      float wwn = wwl[n];
      #pragma unroll
      for (int w = 0; w < 16; ++w) {
        int wj = c4 + w;
        Ml[n * 65 + wj] = Ml[n * 65 + wj] * (1.f - wwn * er[wj]) + wwn * xir[389 + wj];
      }
      #pragma unroll
      for (int w = 0; w < 16; ++w) {
        int m2 = c4 + w;
        float Lv = (n == m2) ? 0.f
                 : ((1.f - wwn - wwl[m2]) * Ll[n * 65 + m2] + wwn * pp[m2]);
        Ll[n * 65 + m2] = Lv;
      }
    }
    __syncthreads();
    // -- fwd/bwd (old wr, new L), read-key sims (new M), new norms
    {
      float f = 0.f, bw2 = 0.f, d = 0.f;
      for (int m2 = 0; m2 < 64; ++m2) {
        float wrm = wrl[wv * 64 + m2];
        f   += Ll[lane * 65 + m2] * wrm;
        bw2 += Ll[m2 * 65 + lane] * wrm;
      }
      fwd[wv * 64 + lane] = f;
      bwd[wv * 64 + lane] = bw2;
      for (int w = 0; w < 64; ++w) d += Ml[lane * 65 + w] * xir[wv * 64 + w];
      simr[wv * 64 + lane] = d;
      float v = xir[wv * 64 + lane];
      float s2 = wsum(v * v);
      if (lane == 0) scal[8 + wv] = sqrtf(s2) + EPSV;
      if (wv == 0) {
        float s = 0.f;
        for (int w = 0; w < 64; ++w) { float m = Ml[lane * 65 + w]; s += m * m; }
        nrmn[lane] = sqrtf(s) + EPSV;
      }
    }
    __syncthreads();
    // -- read content weights, new wr, p update
    {
      float x = simr[wv * 64 + lane] / (nrmn[lane] * scal[8 + wv]) * scal[4 + wv];
      float mx = wmaxr(x);
      float e = expf(x - mx);
      float s = wsum(e);
      float cw = e / s;
      float wrn = scal[16 + wv * 3 + 0] * bwd[wv * 64 + lane]
                + scal[16 + wv * 3 + 1] * cw
                + scal[16 + wv * 3 + 2] * fwd[wv * 64 + lane];
      wrl[wv * 64 + lane] = wrn;
      if (wv == 3) {
        float s3 = wsum(wwl[lane]);
        pp[lane] = (1.f - s3) * pp[lane] + wwl[lane];
      }
    }
    __syncthreads();
    // -- r(t) = wr @ M -> rbuf (bf16 packed, MALL write-through)
    {
      float rv = 0.f;
      for (int n2 = 0; n2 < 64; ++n2) rv += wrl[wv * 64 + n2] * Ml[n2 * 65 + lane];
      unsigned v0 = f2b(rv);
      unsigned v1 = __shfl_down(v0, 1, 64);
      unsigned v2 = __shfl_down(v0, 2, 64);
      unsigned v3 = __shfl_down(v0, 3, 64);
      if ((lane & 3) == 0) {
        u64 pk = (u64)v0 | ((u64)v1 << 16) | ((u64)v2 << 32) | ((u64)v3 << 48);
        st_u64((u64*)(rbuf + blk * (RH * NC) + wv * 64 + lane), pk);
      }
    }
    __syncthreads();                    // drain r stores
    if (tid == 0) add_flag(rdone);      // r(t) published
    // gates x/h parts for t+1 (h(t) global by now; off critical path)
    if (wv < 2 && t < TT - 1) {
      ax0 = f32x4{0.f, 0.f, 0.f, 0.f};
      ax1 = f32x4{0.f, 0.f, 0.f, 0.f};
      x_mfmas(t + 1);
      h_mfmas(t & 1);
    }
  }

  // final y(TT-1): needs r(TT-1)
  if (is_y) {
    wait_cnt(rdone, 32u * (unsigned)TT);
    if (wv >= 2) do_y(TT);
  }
}

extern "C" void kernel_launch(void* const* d_in, const int* in_sizes, int n_in,
                              void* d_out, int out_size, void* d_ws, size_t ws_size,
                              hipStream_t stream) {
  const int*   src    = (const int*)d_in[0];
  const float* emb    = (const float*)d_in[2];
  const float* Wih    = (const float*)d_in[3];
  const float* Whh    = (const float*)d_in[4];
  const float* b_lstm = (const float*)d_in[5];
  const float* W_xi   = (const float*)d_in[6];
  const float* b_xi   = (const float*)d_in[7];
  const float* W_out  = (const float*)d_in[8];
  const float* b_out  = (const float*)d_in[9];
  float* out = (float*)d_out;

  char* ws = (char*)d_ws;
  unsigned*       hdone  = (unsigned*)(ws + WS_HFLG);
  unsigned*       xdone  = (unsigned*)(ws + WS_XDONE);
  unsigned*       rdone  = (unsigned*)(ws + WS_RFLG);
  unsigned short* hbuf   = (unsigned short*)(ws + WS_HBUF);
  unsigned short* rbuf   = (unsigned short*)(ws + WS_RBUF);
  unsigned short* wxbT   = (ws_size >= WS_MIN)   ? (unsigned short*)(ws + WS_WXBT) : nullptr;
  unsigned short* embbuf = (ws_size >= WS_FULL)  ? (unsigned short*)(ws + WS_EMB)  : nullptr;
  float*          xibuf  = (ws_size >= WS_FULL2) ? (float*)(ws + WS_XIB)           : nullptr;

  hipMemsetAsync(d_ws, 0, WS_ZERO, stream);   // counters + h0 + r0
  hipFuncSetAttribute((const void*)dnc_kernel,
                      hipFuncAttributeMaxDynamicSharedMemorySize, SMEM_BYTES);
  dnc_kernel<<<dim3(NBLK), dim3(BS), SMEM_BYTES, stream>>>(
      src, emb, Wih, Whh, b_lstm, W_xi, b_xi, W_out, b_out, out,
      hdone, rdone, xdone, hbuf, rbuf, wxbT, embbuf, xibuf);
}

// Round 14
// 6995.296 us; speedup vs baseline: 9.0294x; 1.1359x over previous
//
#include <hip/hip_runtime.h>

// Persistent-grid DNC encoder for MI355X (gfx950).
// R18 = R17 (7.95 ms) + three cuts on the two remaining serial segments:
//  1) TAGGED xibuf (needs +128KB ws; else falls back to R17 xdone path,
//     then in-block xi): helpers store each xi value as one atomic u64
//     (tag=t+1 | f32 bits) -> discovery IS the data. No drain, no xdone,
//     no detect hop, no separate load. Overwrite-safe: helper(t+1) runs
//     only after all h(t+1) => all r(t) => xi(t) consumed.
//  2) Interior merge: scalar stage folded into roles stage on idle wave 3
//     (wave 2 computes its own free gates, same FP ops) -> 1 barrier less.
//  3) Norm double-buffer: nrmo(t+1) == nrmn(t) -> wave 0's 64x64 norm
//     recompute deleted; parity-swapped LDS buffers (init EPSV).
// FP order preserved everywhere -> bit-identical output.

constexpr int NBLK = 128;
constexpr int BS   = 256;
constexpr int BQ   = 32;
constexpr int TT   = 256;
constexpr int HH   = 512;
constexpr int RH   = 4;
constexpr int NC   = 64;
constexpr int XI   = 471;
constexpr int KG   = 1280;    // gates K = 512(x)+256(r)+512(h)
constexpr int KGP  = 1288;    // padded LDS K stride (bf16)
constexpr int WOP  = 776;     // padded W_out K stride
constexpr float CLIPV = 50000.0f;
constexpr float EPSV  = 1e-6f;

typedef __bf16 bf16x8 __attribute__((ext_vector_type(8)));
typedef float  f32x4  __attribute__((ext_vector_type(4)));
typedef unsigned long long u64;

// ---- LDS layout (bytes) ----
constexpr int OFF_WG   = 0;                      // 16*KGP bf16 = 41216
constexpr int OFF_WO   = OFF_WG  + 16*KGP*2;     // 16*WOP bf16 = 24832
constexpr int OFF_GT   = OFF_WO  + 16*WOP*2;     // 32*17 f32   = 2176
constexpr int OFF_CST  = OFF_GT  + 32*17*4;      // 128 f32     = 512
constexpr int OFF_HLB  = OFF_CST + 512;          // 512 bf16    = 1024
constexpr int OFF_DNC  = OFF_HLB + 1024;
constexpr int D_M    = 0;                        // 64*65 f32
constexpr int D_L    = D_M   + 64*65*4;
constexpr int D_XIR  = D_L   + 64*65*4;          // 480 f32
constexpr int D_WR   = D_XIR + 480*4;
constexpr int D_FWD  = D_WR  + 256*4;
constexpr int D_BWD  = D_FWD + 256*4;
constexpr int D_SIMR = D_BWD + 256*4;
constexpr int D_VEC  = D_SIMR+ 256*4;            // 8 arrays of 64 f32
constexpr int D_SCAL = D_VEC + 8*64*4;           // 32 f32
constexpr int SMEM_BYTES = OFF_DNC + D_SCAL + 32*4;   // 111232

// ---- workspace layout (bytes) ----
constexpr size_t WS_HFLG  = 0;                         // hdone counter line
constexpr size_t WS_XDONE = 128;                       // xdone counter line
constexpr size_t WS_RFLG  = 8192;                      // rdone counter line
constexpr size_t WS_HBUF  = 8192 + 2048;               // 2*32*512 bf16 = 65536
constexpr size_t WS_RBUF  = WS_HBUF + 65536;           // 32*256 bf16   = 16384
constexpr size_t WS_WXBT  = WS_RBUF + 16384;           // 480*512 bf16  = 491520
constexpr size_t WS_EMB   = WS_WXBT + 491520;          // 8192*512 bf16 = 8388608
constexpr size_t WS_MIN   = WS_WXBT + 491520;
constexpr size_t WS_FULL  = WS_EMB + 8388608;
constexpr size_t WS_XIB   = WS_FULL;                   // f32 path: 32*512*4 = 64K
constexpr size_t WS_FULL2 = WS_XIB + 32ull * 512 * 4;
constexpr size_t XIBT_BYTES = 32ull * 512 * 8;         // tagged path: 128K
constexpr size_t WS_FULL3 = WS_XIB + XIBT_BYTES;
constexpr size_t WS_ZERO  = WS_RBUF + 16384;           // counters + hbuf + rbuf

__device__ __forceinline__ unsigned short f2b(float f) {
  unsigned u = __builtin_bit_cast(unsigned, f);
  u += 0x7fffu + ((u >> 16) & 1u);
  return (unsigned short)(u >> 16);
}
__device__ __forceinline__ float sigf(float x) { return 1.0f / (1.0f + expf(-x)); }
__device__ __forceinline__ float softplusf(float x) { return (x > 20.0f) ? x : log1pf(expf(x)); }
__device__ __forceinline__ float wsum(float v) {
  #pragma unroll
  for (int o = 32; o; o >>= 1) v += __shfl_xor(v, o, 64);
  return v;
}
__device__ __forceinline__ float wmaxr(float v) {
  #pragma unroll
  for (int o = 32; o; o >>= 1) v = fmaxf(v, __shfl_xor(v, o, 64));
  return v;
}
__device__ __forceinline__ f32x4 mfma16(bf16x8 a, bf16x8 b, f32x4 c) {
  return __builtin_amdgcn_mfma_f32_16x16x32_bf16(a, b, c, 0, 0, 0);
}
__device__ __forceinline__ void drain_vm() {
  asm volatile("s_waitcnt vmcnt(0)" ::: "memory");
}

// MALL write-through / MALL-direct (relaxed agent atomics)
__device__ __forceinline__ void st_u64(u64* p, u64 v) {
  __hip_atomic_store(p, v, __ATOMIC_RELAXED, __HIP_MEMORY_SCOPE_AGENT);
}
__device__ __forceinline__ u64 ld_u64(const u64* p) {
  return __hip_atomic_load(p, __ATOMIC_RELAXED, __HIP_MEMORY_SCOPE_AGENT);
}
__device__ __forceinline__ unsigned ld_flag(const unsigned* p) {
  return __hip_atomic_load(p, __ATOMIC_RELAXED, __HIP_MEMORY_SCOPE_AGENT);
}
__device__ __forceinline__ void add_flag(unsigned* p) {
  __hip_atomic_fetch_add(p, 1u, __ATOMIC_RELAXED, __HIP_MEMORY_SCOPE_AGENT);
}
struct alignas(16) U64x2 { u64 a, b; };
__device__ __forceinline__ bf16x8 ld_bf16x8_mall(const unsigned short* p) {
  U64x2 v;
  v.a = ld_u64((const u64*)p);
  v.b = ld_u64((const u64*)p + 1);
  return __builtin_bit_cast(bf16x8, v);
}

// wave 0 polls a single shared counter (one request per round), block release
__device__ __forceinline__ void wait_cnt(const unsigned* cnt, unsigned target) {
  if ((threadIdx.x >> 6) == 0) {
    while (ld_flag(cnt) < target) { /* tight spin, single line */ }
  }
  __builtin_amdgcn_fence(__ATOMIC_ACQUIRE, "workgroup");
  __syncthreads();
}

__global__ __launch_bounds__(BS, 1) void dnc_kernel(
    const int* __restrict__ src, const float* __restrict__ emb,
    const float* __restrict__ Wih, const float* __restrict__ Whh,
    const float* __restrict__ b_lstm, const float* __restrict__ W_xi,
    const float* __restrict__ b_xi, const float* __restrict__ W_out,
    const float* __restrict__ b_out, float* __restrict__ out,
    unsigned* __restrict__ hdone, unsigned* __restrict__ rdone,
    unsigned* __restrict__ xdone,
    unsigned short* __restrict__ hbuf, unsigned short* __restrict__ rbuf,
    unsigned short* __restrict__ wxbT_, unsigned short* __restrict__ embbuf_,
    float* __restrict__ xibF, u64* __restrict__ xibT)
{
  extern __shared__ char smem[];
  __bf16* lWg  = (__bf16*)(smem + OFF_WG);
  __bf16* lWo  = (__bf16*)(smem + OFF_WO);
  float*  gt   = (float*)(smem + OFF_GT);
  float*  cst  = (float*)(smem + OFF_CST);
  __bf16* hlb  = (__bf16*)(smem + OFF_HLB);
  char*   dnc  = smem + OFF_DNC;
  float* Ml   = (float*)(dnc + D_M);
  float* Ll   = (float*)(dnc + D_L);
  float* xir  = (float*)(dnc + D_XIR);
  float* wrl  = (float*)(dnc + D_WR);
  float* fwd  = (float*)(dnc + D_FWD);
  float* bwd  = (float*)(dnc + D_BWD);
  float* simr = (float*)(dnc + D_SIMR);
  float* uu   = (float*)(dnc + D_VEC);
  float* pp   = uu + 64;
  float* wwl  = uu + 128;
  float* aas  = uu + 192;
  float* nb0  = uu + 256;     // norm buffer parity 0
  float* nb1  = uu + 320;     // norm buffer parity 1
  float* simw = uu + 384;
  float* er   = uu + 448;
  float* scal = (float*)(dnc + D_SCAL);
  // scal: [0]beta_w [1]g_a [2]g_w [3]wknrm [4..7]beta_r [16..27]pi

  const int tid  = threadIdx.x;
  const int blk  = blockIdx.x;
  const int lane = tid & 63;
  const int wv   = tid >> 6;
  const int q    = lane >> 4;
  const int n16  = lane & 15;
  const int j0   = blk << 2;    // h slice: columns j0..j0+3
  const __bf16* wxbT = (const __bf16*)wxbT_;
  const __bf16* embbuf = (const __bf16*)embbuf_;
  const bool is_dnc = (blk < BQ);
  const bool is_y   = (blk >= 64 && blk < 96);
  const bool is_xi  = (blk >= 96 && blk < 126) && (xibF || xibT) && (wxbT_ != nullptr);

  // ---------------- prepass ----------------
  for (int e = tid; e < 16 * KG; e += BS) {
    int k = e >> 4, cc = e & 15;
    int gcol = ((cc >> 2) << 9) + j0 + (cc & 3);   // gate*512 + h-col
    float w = (k < 768) ? Wih[k * 2048 + gcol] : Whh[(k - 768) * 2048 + gcol];
    lWg[cc * KGP + k] = (__bf16)w;
  }
  if (is_y) {
    for (int e = tid; e < 16 * 768; e += BS) {
      int k = e >> 4, cc = e & 15;
      int col = ((blk - 64) << 4) + cc;
      lWo[cc * WOP + k] = (__bf16)W_out[k * HH + col];
    }
  }
  if (wxbT_) {
    // W_xi -> bf16 in MFMA-FRAGMENT order (coalesced, L1-resident slices)
    for (int w = blk * BS + tid; w < 61440; w += NBLK * BS) {
      int e = w << 2;
      int jb    = e & 7;
      int lane_ = (e >> 3) & 63;
      int f     = e >> 9;              // tile*16 + kt
      int col   = (f >> 4) * 16 + (lane_ & 15);
      int k0    = (f & 15) * 32 + (lane_ >> 4) * 8 + jb;
      u64 pk = 0;
      if (col < XI) {
        #pragma unroll
        for (int j = 0; j < 4; ++j) {
          unsigned short us = f2b(W_xi[(size_t)(k0 + j) * XI + col]);
          pk |= (u64)us << (16 * j);
        }
      }
      st_u64((u64*)wxbT_ + w, pk);
    }
  }
  if (embbuf_) { // gather emb[src] -> bf16 (MALL write-through)
    for (int rr = blk * 2 + (tid >> 7); rr < BQ * TT; rr += NBLK * 2) {
      const int t128 = tid & 127;
      const float* s = emb + (size_t)src[rr] * HH;
      float4 v = *(const float4*)(s + t128 * 4);
      u64 pk = (u64)f2b(v.x) | ((u64)f2b(v.y) << 16)
             | ((u64)f2b(v.z) << 32) | ((u64)f2b(v.w) << 48);
      st_u64((u64*)(embbuf_ + (size_t)rr * HH + t128 * 4), pk);
    }
  }
  if (tid < 128) cst[tid] = 0.0f;
  if (is_dnc) {
    for (int e = tid; e < 64 * 65; e += BS) { Ml[e] = 0.0f; Ll[e] = 0.0f; }
    if (tid < 64) { uu[tid] = 0.0f; pp[tid] = 0.0f; wwl[tid] = 0.0f; nb0[tid] = EPSV; }
    wrl[tid] = 0.0f;
  }
  __syncthreads();
  if (tid == 0) add_flag(hdone);        // prepass published (+1 of 128)

  // persistent gates accumulators (waves 0,1)
  f32x4 ax0 = {0.f, 0.f, 0.f, 0.f}, ax1 = {0.f, 0.f, 0.f, 0.f};
  const int bb = ((wv & 1) << 4) + n16;          // gates A-row (waves 0,1)

  // x-part: 16 MFMAs (embedding of step tt)
  auto x_mfmas = [&](int tt) {
    const __bf16* eb = embbuf ? (embbuf + ((size_t)bb * TT + tt) * HH) : nullptr;
    const float* ep = embbuf ? nullptr
                             : (emb + (size_t)src[bb * TT + tt] * HH + (q << 3));
    #pragma unroll
    for (int ks = 0; ks < 16; ++ks) {
      const int kq = (ks << 5) + (q << 3);
      bf16x8 A;
      if (eb) {
        A = *(const bf16x8*)(eb + kq);
      } else {
        const float* p = ep + (ks << 5);
        #pragma unroll
        for (int j = 0; j < 8; ++j) A[j] = (__bf16)p[j];
      }
      bf16x8 Bf = *(const bf16x8*)(lWg + n16 * KGP + kq);
      if (ks & 1) ax1 = mfma16(A, Bf, ax1); else ax0 = mfma16(A, Bf, ax0);
    }
  };
  // h-part: 16 MFMAs reading h(slot) MALL-direct
  auto h_mfmas = [&](int slot) {
    const unsigned short* hp = hbuf + slot * (BQ * HH);
    #pragma unroll
    for (int ks = 16; ks < 32; ++ks) {
      const int off = ((ks - 16) << 5) + (q << 3);
      bf16x8 A = ld_bf16x8_mall(hp + bb * HH + off);
      bf16x8 Bf = *(const bf16x8*)(lWg + n16 * KGP + 768 + off);
      if (ks & 1) ax1 = mfma16(A, Bf, ax1); else ax0 = mfma16(A, Bf, ax0);
    }
  };
  // r-part: 8 MFMAs reading rbuf MALL-direct; then write gt
  auto r_mfmas = [&]() {
    #pragma unroll
    for (int ks = 32; ks < 40; ++ks) {
      const int off = ((ks - 32) << 5) + (q << 3);
      bf16x8 A = ld_bf16x8_mall(rbuf + bb * (RH * NC) + off);
      bf16x8 Bf = *(const bf16x8*)(lWg + n16 * KGP + 512 + off);
      if (ks & 1) ax1 = mfma16(A, Bf, ax1); else ax0 = mfma16(A, Bf, ax0);
    }
    const int gcol = ((n16 >> 2) << 9) + j0 + (n16 & 3);
    const float bias = b_lstm[gcol];
    #pragma unroll
    for (int j = 0; j < 4; ++j)
      gt[(((wv & 1) << 4) + (q << 2) + j) * 17 + n16] = ax0[j] + ax1[j] + bias;
  };
  // y(t-1): waves 2,3 of y-blocks; needs h(t-1) and r(t-1)
  auto do_y = [&](int t) {
    const unsigned short* hp = hbuf + ((t + 1) & 1) * (BQ * HH);
    const int mt = wv - 2;
    const int bby = (mt << 4) + n16;
    f32x4 a0 = {0.f, 0.f, 0.f, 0.f}, a1 = {0.f, 0.f, 0.f, 0.f};
    #pragma unroll
    for (int ks = 0; ks < 24; ++ks) {
      const int kq = (ks << 5) + (q << 3);
      bf16x8 A = (ks < 16) ? ld_bf16x8_mall(hp + bby * HH + kq)
                           : ld_bf16x8_mall(rbuf + bby * (RH * NC) + (kq - 512));
      bf16x8 Bf = *(const bf16x8*)(lWo + n16 * WOP + kq);
      if (ks & 1) a1 = mfma16(A, Bf, a1); else a0 = mfma16(A, Bf, a0);
    }
    const int col = ((blk - 64) << 4) + n16;
    const float bias = b_out[col];
    #pragma unroll
    for (int j = 0; j < 4; ++j) {
      int row = (mt << 4) + (q << 2) + j;
      float y = a0[j] + a1[j] + bias;
      y = fminf(fmaxf(y, -CLIPV), CLIPV);
      out[(size_t)row * (TT * HH) + (size_t)(t - 1) * HH + col] = y;
    }
  };
  // xi helper (blocks 96..125, waves 2,3): cols 16ct..16ct+15, all 32 batches
  auto do_xi = [&](int t) {
    const unsigned short* hp = hbuf + (t & 1) * (BQ * HH)
                             + (size_t)((((wv - 2) << 4) + n16) * HH) + (q << 3);
    const int ct = blk - 96;
    f32x4 acc = {0.f, 0.f, 0.f, 0.f};
    bf16x8 A[8];
    #pragma unroll
    for (int kt = 0; kt < 8; ++kt) A[kt] = ld_bf16x8_mall(hp + (kt << 5));
    #pragma unroll
    for (int kt = 0; kt < 8; ++kt) {
      bf16x8 Bf = *(const bf16x8*)(wxbT + (((size_t)(ct << 4) + kt) << 9) + (lane << 3));
      acc = mfma16(A[kt], Bf, acc);
    }
    #pragma unroll
    for (int kt = 0; kt < 8; ++kt) A[kt] = ld_bf16x8_mall(hp + ((8 + kt) << 5));
    #pragma unroll
    for (int kt = 0; kt < 8; ++kt) {
      bf16x8 Bf = *(const bf16x8*)(wxbT + (((size_t)(ct << 4) + 8 + kt) << 9) + (lane << 3));
      acc = mfma16(A[kt], Bf, acc);
    }
    const int col = (ct << 4) + n16;
    const float bias = (col < XI) ? b_xi[col] : 0.0f;
    if (xibT) {
      // tagged: one u64 per value, tag = t+1 in high dword; no drain/flag
      #pragma unroll
      for (int j = 0; j < 4; ++j) {
        float v = acc[j] + bias;
        int batch = ((wv - 2) << 4) + (q << 2) + j;
        st_u64(xibT + ((size_t)batch << 9) + col,
               (u64)__builtin_bit_cast(unsigned, v) | ((u64)(unsigned)(t + 1) << 32));
      }
    } else {
      #pragma unroll
      for (int j = 0; j < 4; ++j) {
        float v = acc[j] + bias;
        unsigned lo = __builtin_bit_cast(unsigned, v);
        unsigned hi = __shfl_down(lo, 1, 64);
        if (!(n16 & 1)) {
          int batch = ((wv - 2) << 4) + (q << 2) + j;
          st_u64((u64*)(xibF + ((size_t)batch << 9) + col),
                 (u64)lo | ((u64)hi << 32));
        }
      }
      drain_vm();
      if (lane == 0) add_flag(xdone);   // +1 per wave -> 60 per step
    }
  };

  // pre-loop: wait all prepass, then x-part(0). h(-1)=0, r(-1)=0.
  wait_cnt(hdone, 128u);
  if (wv < 2) x_mfmas(0);

  for (int t = 0; t < TT; ++t) {
    unsigned short* hcur = hbuf + (t & 1) * (BQ * HH);

    if (t > 0) wait_cnt(rdone, 32u * (unsigned)t);  // r(t-1) (t=0: zeros)
    if (wv < 2) {
      r_mfmas();                          // gates(t) complete -> gt
    } else if (is_y && t > 0) {
      do_y(t);                            // y(t-1): h(t-1), r(t-1)
    }
    __syncthreads();
    if (tid < BQ) {                       // LSTM: batch=tid, 4 h-cols
      const int b = tid;
      u64 hv = 0;
      #pragma unroll
      for (int i = 0; i < 4; ++i) {
        float g_i = gt[b * 17 + i],     g_f = gt[b * 17 + 4 + i];
        float g_g = gt[b * 17 + 8 + i], g_o = gt[b * 17 + 12 + i];
        float c = cst[b * 4 + i];
        c = sigf(g_f) * c + sigf(g_i) * tanhf(g_g);
        float h = sigf(g_o) * tanhf(c);
        cst[b * 4 + i] = c;
        hv |= (u64)f2b(h) << (16 * i);
      }
      st_u64((u64*)(hcur + b * HH + j0), hv);
    }
    __syncthreads();                      // drain h stores to MALL
    if (tid == 0) add_flag(hdone);        // h(t) published

    if (!is_dnc) {
      if (is_xi) {
        // helpers: detect h(t) immediately, then xi; gates prefetch after
        wait_cnt(hdone, 128u * (unsigned)(t + 2));
        if (wv >= 2) {
          do_xi(t);
        } else if (t < TT - 1) {
          ax0 = f32x4{0.f, 0.f, 0.f, 0.f};
          ax1 = f32x4{0.f, 0.f, 0.f, 0.f};
          x_mfmas(t + 1);
          h_mfmas(t & 1);
        }
      } else {
        if (wv < 2 && t < TT - 1) {
          ax0 = f32x4{0.f, 0.f, 0.f, 0.f};
          ax1 = f32x4{0.f, 0.f, 0.f, 0.f};
          x_mfmas(t + 1);
        }
        wait_cnt(hdone, 128u * (unsigned)(t + 2));
        if (wv < 2 && t < TT - 1) h_mfmas(t & 1);
      }
      continue;
    }

    // ---------------- DNC block: phase C(t) ----------------
    if (xibT && wxbT_) {
      // tagged poll: discovery IS the data (no fence needed: tag+value atomic)
      const u64* xb = xibT + ((size_t)blk << 9);
      const unsigned tg = (unsigned)(t + 1);
      u64 v1 = 0, v2 = 0;
      bool o1 = false, o2 = (tid >= 224);
      for (;;) {
        if (!o1) { v1 = ld_u64(xb + tid);       o1 = ((unsigned)(v1 >> 32) == tg); }
        if (!o2) { v2 = ld_u64(xb + 256 + tid); o2 = ((unsigned)(v2 >> 32) == tg); }
        if (o1 && o2) break;
      }
      xir[tid] = __builtin_bit_cast(float, (unsigned)v1);
      if (tid < 224) xir[256 + tid] = __builtin_bit_cast(float, (unsigned)v2);
      __syncthreads();                            // xir ready
    } else if (xibF && wxbT_) {
      wait_cnt(xdone, 60u * (unsigned)(t + 1));   // xi(t) published
      if (tid < 240) {                            // 480 f32, coalesced u64
        u64 v = ld_u64((const u64*)(xibF + ((size_t)blk << 9)) + tid);
        xir[tid * 2]     = __builtin_bit_cast(float, (unsigned)v);
        xir[tid * 2 + 1] = __builtin_bit_cast(float, (unsigned)(v >> 32));
      }
      __syncthreads();
    } else {
      // fallback: in-block xi (R16 path)
      wait_cnt(hdone, 128u * (unsigned)(t + 2));
      if (tid < 128) {
        u64 hv = ld_u64((const u64*)(hcur + blk * HH + tid * 4));
        #pragma unroll
        for (int i = 0; i < 4; ++i)
          hlb[tid * 4 + i] = __builtin_bit_cast(__bf16, (unsigned short)(hv >> (16 * i)));
      }
      __syncthreads();
      {
        constexpr int TPW = 8;
        f32x4 acc[TPW];
        #pragma unroll
        for (int i = 0; i < TPW; ++i) acc[i] = f32x4{0.f, 0.f, 0.f, 0.f};
        const int ct0 = wv * TPW;
        const int ntile = (ct0 + TPW <= 30) ? TPW : (30 - ct0);
        for (int kt = 0; kt < 16; ++kt) {
          bf16x8 Bf = {};
          if (n16 == 0) Bf = *(const bf16x8*)(hlb + kt * 32 + (q << 3));
          if (wxbT) {
            #pragma unroll
            for (int i = 0; i < TPW; ++i) {
              if (i < ntile) {
                const __bf16* ap = wxbT
                    + (((size_t)(ct0 + i) * 16 + kt) << 9) + (lane << 3);
                acc[i] = mfma16(*(const bf16x8*)ap, Bf, acc[i]);
              }
            }
          } else {
            #pragma unroll
            for (int i = 0; i < TPW; ++i) {
              if (i < ntile) {
                const int col = (ct0 + i) * 16 + n16;
                bf16x8 Af;
                #pragma unroll
                for (int j = 0; j < 8; ++j)
                  Af[j] = (col < XI) ? (__bf16)W_xi[(size_t)(kt * 32 + (q << 3) + j) * XI + col]
                                     : (__bf16)0.0f;
                acc[i] = mfma16(Af, Bf, acc[i]);
              }
            }
          }
        }
        if (n16 == 0) {
          const int rowb = (lane >> 4) * 4;
          #pragma unroll
          for (int i = 0; i < TPW; ++i) {
            if (i < ntile) {
              #pragma unroll
              for (int j = 0; j < 4; ++j) {
                int col = (ct0 + i) * 16 + rowb + j;
                if (col < XI) xir[col] = acc[i][j] + b_xi[col];
              }
            }
          }
        }
      }
      __syncthreads();
    }
    const float* nbR = (t & 1) ? nb1 : nb0;   // old M row norms
    float*       nbW = (t & 1) ? nb0 : nb1;   // new M row norms
    // ---- merged roles + scalars stage ----
    if (wv == 1) {                            // simw = M . write_key + wknrm
      float d = 0.f;
      for (int w = 0; w < 64; ++w) d += Ml[lane * 65 + w] * xir[260 + w];
      simw[lane] = d;
      float v = xir[260 + lane];
      float s2 = wsum(v * v);
      if (lane == 0) scal[3] = sqrtf(s2) + EPSV;
    } else if (wv == 2) {                     // usage + sort + allocation
      float fr0 = sigf(xir[453]), fr1 = sigf(xir[454]);
      float fr2 = sigf(xir[455]), fr3 = sigf(xir[456]);
      float psi = (1.f - fr0 * wrl[lane]) * (1.f - fr1 * wrl[64 + lane])
                * (1.f - fr2 * wrl[128 + lane]) * (1.f - fr3 * wrl[192 + lane]);
      float un = uu[lane], w_ = wwl[lane];
      un = (un + w_ - un * w_) * psi;
      uu[lane] = un;
      float v = un; int id = lane;
      for (int k = 2; k <= 64; k <<= 1) {
        for (int j2 = k >> 1; j2 > 0; j2 >>= 1) {
          float ov = __shfl_xor(v, j2, 64);
          int   oi = __shfl_xor(id, j2, 64);
          bool up    = ((lane & k) == 0);
          bool lower = ((lane & j2) == 0);
          bool lt = (v < ov) || (v == ov && id < oi);
          bool keep = (lower == up) ? lt : !lt;
          if (!keep) { v = ov; id = oi; }
        }
      }
      float cp = v;
      for (int d2 = 1; d2 < 64; d2 <<= 1) {
        float o = __shfl_up(cp, d2, 64);
        if (lane >= d2) cp *= o;
      }
      float pe = __shfl_up(cp, 1, 64);
      if (lane == 0) pe = 1.0f;
      aas[id] = (1.0f - v) * pe;
    } else if (wv == 3) {                     // scalars + erase (was own stage)
      if (lane == 0) {
        scal[0] = 1.0f + softplusf(xir[324]);   // beta_w
        scal[1] = sigf(xir[457]);               // g_a
        scal[2] = sigf(xir[458]);               // g_w
      }
      if (lane >= 4 && lane < 8) {
        int r = lane - 4;
        scal[4 + r] = 1.0f + softplusf(xir[256 + r]);   // beta_r
        float p0 = xir[459 + r * 3], p1 = xir[460 + r * 3], p2 = xir[461 + r * 3];
        float m = fmaxf(p0, fmaxf(p1, p2));
        float e0 = expf(p0 - m), e1 = expf(p1 - m), e2 = expf(p2 - m);
        float s = e0 + e1 + e2;
        scal[16 + r * 3 + 0] = e0 / s;
        scal[16 + r * 3 + 1] = e1 / s;
        scal[16 + r * 3 + 2] = e2 / s;
      }
      er[lane] = sigf(xir[325 + lane]);
    }
    __syncthreads();
    // -- write content weights -> ww (wave 0; nbR = carried old norms)
    if (wv == 0) {
      float x = simw[lane] / (nbR[lane] * scal[3]) * scal[0];
      float mx = wmaxr(x);
      float e = expf(x - mx);
      float s = wsum(e);
      float cw = e / s;
      wwl[lane] = scal[2] * (scal[1] * aas[lane] + (1.f - scal[1]) * cw);
    }
    __syncthreads();
    // -- M and L updates (old p)
    {
      const int n = tid >> 2, c4 = (tid & 3) << 4;
      float wwn = wwl[n];
      #pragma unroll
      for (int w = 0; w < 16; ++w) {
        int wj = c4 + w;
        Ml[n * 65 + wj] = Ml[n * 65 + wj] * (1.f - wwn * er[wj]) + wwn * xir[389 + wj];
      }
      #pragma unroll
      for (int w = 0; w < 16; ++w) {
        int m2 = c4 + w;
        float Lv = (n == m2) ? 0.f
                 : ((1.f - wwn - wwl[m2]) * Ll[n * 65 + m2] + wwn * pp[m2]);
        Ll[n * 65 + m2] = Lv;
      }
    }
    __syncthreads();
    // -- fwd/bwd (old wr, new L), read-key sims (new M), new norms -> nbW
    {
      float f = 0.f, bw2 = 0.f, d = 0.f;
      for (int m2 = 0; m2 < 64; ++m2) {
        float wrm = wrl[wv * 64 + m2];
        f   += Ll[lane * 65 + m2] * wrm;
        bw2 += Ll[m2 * 65 + lane] * wrm;
      }
      fwd[wv * 64 + lane] = f;
      bwd[wv * 64 + lane] = bw2;
      for (int w = 0; w < 64; ++w) d += Ml[lane * 65 + w] * xir[wv * 64 + w];
      simr[wv * 64 + lane] = d;
      float v = xir[wv * 64 + lane];
      float s2 = wsum(v * v);
      if (lane == 0) scal[8 + wv] = sqrtf(s2) + EPSV;
      if (wv == 0) {
        float s = 0.f;
        for (int w = 0; w < 64; ++w) { float m = Ml[lane * 65 + w]; s += m * m; }
        nbW[lane] = sqrtf(s) + EPSV;
      }
    }
    __syncthreads();
    // -- read content weights, new wr, p update
    {
      float x = simr[wv * 64 + lane] / (nbW[lane] * scal[8 + wv]) * scal[4 + wv];
      float mx = wmaxr(x);
      float e = expf(x - mx);
      float s = wsum(e);
      float cw = e / s;
      float wrn = scal[16 + wv * 3 + 0] * bwd[wv * 64 + lane]
                + scal[16 + wv * 3 + 1] * cw
                + scal[16 + wv * 3 + 2] * fwd[wv * 64 + lane];
      wrl[wv * 64 + lane] = wrn;
      if (wv == 3) {
        float s3 = wsum(wwl[lane]);
        pp[lane] = (1.f - s3) * pp[lane] + wwl[lane];
      }
    }
    __syncthreads();
    // -- r(t) = wr @ M -> rbuf (bf16 packed, MALL write-through)
    {
      float rv = 0.f;
      for (int n2 = 0; n2 < 64; ++n2) rv += wrl[wv * 64 + n2] * Ml[n2 * 65 + lane];
      unsigned v0 = f2b(rv);
      unsigned v1 = __shfl_down(v0, 1, 64);
      unsigned v2 = __shfl_down(v0, 2, 64);
      unsigned v3 = __shfl_down(v0, 3, 64);
      if ((lane & 3) == 0) {
        u64 pk = (u64)v0 | ((u64)v1 << 16) | ((u64)v2 << 32) | ((u64)v3 << 48);
        st_u64((u64*)(rbuf + blk * (RH * NC) + wv * 64 + lane), pk);
      }
    }
    __syncthreads();                    // drain r stores
    if (tid == 0) add_flag(rdone);      // r(t) published
    // gates x/h parts for t+1 (h(t) globally visible via xi transitivity)
    if (wv < 2 && t < TT - 1) {
      ax0 = f32x4{0.f, 0.f, 0.f, 0.f};
      ax1 = f32x4{0.f, 0.f, 0.f, 0.f};
      x_mfmas(t + 1);
      h_mfmas(t & 1);
    }
  }

  // final y(TT-1): needs r(TT-1)
  if (is_y) {
    wait_cnt(rdone, 32u * (unsigned)TT);
    if (wv >= 2) do_y(TT);
  }
}

extern "C" void kernel_launch(void* const* d_in, const int* in_sizes, int n_in,
                              void* d_out, int out_size, void* d_ws, size_t ws_size,
                              hipStream_t stream) {
  const int*   src    = (const int*)d_in[0];
  const float* emb    = (const float*)d_in[2];
  const float* Wih    = (const float*)d_in[3];
  const float* Whh    = (const float*)d_in[4];
  const float* b_lstm = (const float*)d_in[5];
  const float* W_xi   = (const float*)d_in[6];
  const float* b_xi   = (const float*)d_in[7];
  const float* W_out  = (const float*)d_in[8];
  const float* b_out  = (const float*)d_in[9];
  float* out = (float*)d_out;

  char* ws = (char*)d_ws;
  unsigned*       hdone  = (unsigned*)(ws + WS_HFLG);
  unsigned*       xdone  = (unsigned*)(ws + WS_XDONE);
  unsigned*       rdone  = (unsigned*)(ws + WS_RFLG);
  unsigned short* hbuf   = (unsigned short*)(ws + WS_HBUF);
  unsigned short* rbuf   = (unsigned short*)(ws + WS_RBUF);
  unsigned short* wxbT   = (ws_size >= WS_MIN)   ? (unsigned short*)(ws + WS_WXBT) : nullptr;
  unsigned short* embbuf = (ws_size >= WS_FULL)  ? (unsigned short*)(ws + WS_EMB)  : nullptr;
  const bool tagged      = (ws_size >= WS_FULL3);
  u64*   xibT  = tagged ? (u64*)(ws + WS_XIB) : nullptr;
  float* xibF  = (!tagged && ws_size >= WS_FULL2) ? (float*)(ws + WS_XIB) : nullptr;

  hipMemsetAsync(d_ws, 0, WS_ZERO, stream);   // counters + h0 + r0
  if (tagged)
    hipMemsetAsync(ws + WS_XIB, 0, XIBT_BYTES, stream);  // clear tags
  hipFuncSetAttribute((const void*)dnc_kernel,
                      hipFuncAttributeMaxDynamicSharedMemorySize, SMEM_BYTES);
  dnc_kernel<<<dim3(NBLK), dim3(BS), SMEM_BYTES, stream>>>(
      src, emb, Wih, Whh, b_lstm, W_xi, b_xi, W_out, b_out, out,
      hdone, rdone, xdone, hbuf, rbuf, wxbT, embbuf, xibF, xibT);
}